// Round 1
// 436.578 us; speedup vs baseline: 1.0999x; 1.0999x over previous
//
#include <hip/hip_runtime.h>
#include <hip/hip_bf16.h>

typedef __hip_bfloat16 bf16;
typedef unsigned int uint;
typedef unsigned short ushort;
typedef __attribute__((ext_vector_type(8))) short short8;   // 8 bf16 = 4 VGPR
typedef __attribute__((ext_vector_type(4))) float float4v;  // MFMA acc

__device__ __forceinline__ float lo2f(uint v) { return __uint_as_float(v << 16); }
__device__ __forceinline__ float hi2f(uint v) { return __uint_as_float(v & 0xffff0000u); }
__device__ __forceinline__ ushort f2bu(float v) {
  union { bf16 h; ushort u; } x;
  x.h = __float2bfloat16(v);
  return x.u;
}
__device__ __forceinline__ uint packbf2(float a, float b) {
  return (uint)f2bu(a) | ((uint)f2bu(b) << 16);
}

#define BSH 8          // bucket shift: 256 nodes per bucket
#define NBK_MAX 391    // max buckets (txn side)

// ======================= fused weight transpose (6 jobs, 1 launch) ===========
struct TJob { const float* wl; const float* wr; ushort* dst; int da, k, ncol, boff; };
struct TJobs { TJob j[6]; };

__global__ void transpose6_kernel(TJobs js) {
  int b = blockIdx.x;
  int jj = 0;
#pragma unroll
  for (int t = 1; t < 6; ++t)
    if (b >= js.j[t].boff) jj = t;
  const TJob J = js.j[jj];
  int i = (b - J.boff) * 256 + threadIdx.x;
  if (i >= J.k * J.ncol) return;
  int k = i / J.ncol, c = i - k * J.ncol;
  const float* srcp = (k < J.da) ? (J.wl + (long long)k * J.ncol)
                                 : (J.wr + (long long)(k - J.da) * J.ncol);
  J.dst[(long long)c * J.k + k] = f2bu(srcp[c]);
}

// ======================= CSR build, two-level counting sort ==================
// Phase 1: coarse histogram of dst>>BSH (LDS per block, atomic merge).
__global__ void bhist_kernel(const int* __restrict__ dA, int* __restrict__ cA, int nbkA,
                             const int* __restrict__ dB, int* __restrict__ cB, int nbkB,
                             int E, int chA) {
  __shared__ int h[NBK_MAX];
  int b = blockIdx.x;
  const int* dst; int* gc; int nbk;
  if (b < chA) { dst = dA; gc = cA; nbk = nbkA; }
  else         { b -= chA; dst = dB; gc = cB; nbk = nbkB; }
  for (int i = threadIdx.x; i < nbk; i += 256) h[i] = 0;
  __syncthreads();
  int e0 = b * 4096;
  for (int j = 0; j < 16; ++j) {
    int e = e0 + j * 256 + threadIdx.x;
    if (e < E) {
      uint B = (uint)dst[e] >> BSH;
      if (B < (uint)nbk) atomicAdd(&h[B], 1);
    }
  }
  __syncthreads();
  for (int i = threadIdx.x; i < nbk; i += 256)
    if (h[i]) atomicAdd(&gc[i], h[i]);
}

// Phase 2: exclusive scan of bucket counts -> bucket offsets + cursors.
__global__ void bscan_kernel(const int* __restrict__ cA, int* __restrict__ oA,
                             int* __restrict__ uA, int nbkA,
                             const int* __restrict__ cB, int* __restrict__ oB,
                             int* __restrict__ uB, int nbkB) {
  __shared__ int s[512];
  const int* cnt; int* off; int* cur; int nbk;
  if (blockIdx.x == 0) { cnt = cA; off = oA; cur = uA; nbk = nbkA; }
  else                 { cnt = cB; off = oB; cur = uB; nbk = nbkB; }
  int t = threadIdx.x;
  int v = (t < nbk) ? cnt[t] : 0;
  s[t] = v;
  __syncthreads();
  for (int o = 1; o < 512; o <<= 1) {
    int x = (t >= o) ? s[t - o] : 0;
    __syncthreads();
    s[t] += x;
    __syncthreads();
  }
  if (t < nbk) { int ex = s[t] - v; off[t] = ex; cur[t] = ex; }
  if (t == nbk - 1) off[nbk] = s[t];
}

// Phase 3: multisplit — scatter (src,dst) into bucket-sorted uint2 array.
// Per-block LDS ranking => per (block,bucket) contiguous write runs.
__global__ void multisplit_kernel(const int* __restrict__ sA, const int* __restrict__ dA,
                                  int* __restrict__ uA, uint2* __restrict__ seA, int nbkA,
                                  const int* __restrict__ sB, const int* __restrict__ dB,
                                  int* __restrict__ uB, uint2* __restrict__ seB, int nbkB,
                                  int E, int chA) {
  __shared__ int cnt[NBK_MAX];
  __shared__ int base[NBK_MAX];
  int b = blockIdx.x;
  const int *src, *dst; int* gcur; uint2* se; int nbk;
  if (b < chA) { src = sA; dst = dA; gcur = uA; se = seA; nbk = nbkA; }
  else         { b -= chA; src = sB; dst = dB; gcur = uB; se = seB; nbk = nbkB; }
  for (int i = threadIdx.x; i < nbk; i += 256) cnt[i] = 0;
  __syncthreads();
  int e0 = b * 4096;
  int mys[16], myd[16], myb[16], myr[16];
#pragma unroll
  for (int j = 0; j < 16; ++j) {
    int e = e0 + j * 256 + threadIdx.x;
    int s = 0, d = 0, bb = -1, r = 0;
    if (e < E) {
      s = src[e]; d = dst[e];
      uint B = (uint)d >> BSH;
      if (B < (uint)nbk) { bb = (int)B; r = atomicAdd(&cnt[bb], 1); }
    }
    mys[j] = s; myd[j] = d; myb[j] = bb; myr[j] = r;
  }
  __syncthreads();
  for (int i = threadIdx.x; i < nbk; i += 256) {
    int c = cnt[i];
    base[i] = c ? atomicAdd(&gcur[i], c) : 0;
  }
  __syncthreads();
#pragma unroll
  for (int j = 0; j < 16; ++j) {
    if (myb[j] >= 0) {
      uint2 v; v.x = (uint)mys[j]; v.y = (uint)myd[j];
      se[base[myb[j]] + myr[j]] = v;
    }
  }
}

// Phase 4: per-bucket fine CSR — one block per bucket, all ranking in LDS.
__global__ void csr_fine_kernel(const uint2* __restrict__ seA, const int* __restrict__ boA,
                                int* __restrict__ offA, int* __restrict__ csrA, int nA, int nbkA,
                                const uint2* __restrict__ seB, const int* __restrict__ boB,
                                int* __restrict__ offB, int* __restrict__ csrB, int nB) {
  __shared__ int s[256];
  __shared__ int cur[256];
  int b = blockIdx.x;
  const uint2* se; const int* bo; int* off; int* csr; int n;
  if (b < nbkA) { se = seA; bo = boA; off = offA; csr = csrA; n = nA; }
  else          { b -= nbkA; se = seB; bo = boB; off = offB; csr = csrB; n = nB; }
  int t = threadIdx.x;
  int ebeg = bo[b], eend = bo[b + 1];
  // local degree histogram
  cur[t] = 0;
  __syncthreads();
  for (int i = ebeg + t; i < eend; i += 256)
    atomicAdd(&cur[se[i].y & 255], 1);
  __syncthreads();
  int v = cur[t];
  s[t] = v;
  __syncthreads();
  for (int o = 1; o < 256; o <<= 1) {
    int x = (t >= o) ? s[t - o] : 0;
    __syncthreads();
    s[t] += x;
    __syncthreads();
  }
  int excl = s[t] - v;
  int node = b * 256 + t;
  if (node < n) off[node] = ebeg + excl;
  if (node == n - 1) off[n] = ebeg + excl + v;
  cur[t] = excl;
  __syncthreads();
  for (int i = ebeg + t; i < eend; i += 256) {
    uint2 e = se[i];
    int pos = ebeg + atomicAdd(&cur[e.y & 255], 1);
    csr[pos] = (int)e.x;
  }
}

// ======================= pull aggregation (mean, bf16 out) — R8-validated ====
template <int D, bool XBF>
__global__ __launch_bounds__(256) void pull_mean_kernel(
    const int* __restrict__ off, const int* __restrict__ csr,
    const void* __restrict__ x, bf16* __restrict__ mean, int n, int nsrc) {
  constexpr int LPR = D / 4;          // lanes per row (4 elems per lane)
  constexpr int PAR = 64 / LPR;       // edges in parallel
  int node = blockIdx.x * 4 + (threadIdx.x >> 6);
  if (node >= n) return;  // wave-uniform
  int lane = threadIdx.x & 63;
  int h = lane / LPR, col = lane % LPR;
  int beg = off[node], deg = off[node + 1] - beg;
  float inv = 1.0f / fmaxf((float)deg, 1.0f);
  float a0 = 0.f, a1 = 0.f, a2 = 0.f, a3 = 0.f;
  for (int i = h; i < deg; i += PAR) {
    int s = csr[beg + i];
    s = ((unsigned)s < (unsigned)nsrc) ? s : 0;
    if (XBF) {
      uint2 v = ((const uint2*)x)[(long long)s * LPR + col];
      a0 += lo2f(v.x); a1 += hi2f(v.x); a2 += lo2f(v.y); a3 += hi2f(v.y);
    } else {
      float4 v = ((const float4*)x)[(long long)s * LPR + col];
      a0 += v.x; a1 += v.y; a2 += v.z; a3 += v.w;
    }
  }
#pragma unroll
  for (int m = LPR; m < 64; m <<= 1) {
    a0 += __shfl_xor(a0, m); a1 += __shfl_xor(a1, m);
    a2 += __shfl_xor(a2, m); a3 += __shfl_xor(a3, m);
  }
  if (h == 0) {
    uint2 o2;
    o2.x = packbf2(a0 * inv, a1 * inv);
    o2.y = packbf2(a2 * inv, a3 * inv);
    ((uint2*)mean)[(long long)node * LPR + col] = o2;
  }
}

// ======================= MFMA GEMM (no LDS, branch-free, MT row-tiles) =======
// MT = 16-row M-tiles per wave. B fragments (weights, L2/L3-resident) are
// loaded ONCE per (kt,t) and reused across MT MFMAs: per-row B traffic drops
// MT-fold and the unrolled loop exposes MT+NCT independent loads per kt so
// the global-load stream pipelines instead of serializing (the 78us/3%-MfmaUtil
// latency wall of the MT=1 version).
#define AT_BF16 0
#define AT_F32  1
template <int KT, int NCT, int K0T, int A0T, int A1T, bool OUTF32, int MT>
__global__ __launch_bounds__(256, 2) void gemm_kernel(
    const void* __restrict__ A0, int lda0,
    const void* __restrict__ A1, int lda1,
    const ushort* __restrict__ Wt, const float* __restrict__ bias,
    void* __restrict__ C, long long cbase, int ldc, int n, int relu) {
  constexpr int K = KT * 32;
  int tid = threadIdx.x;
  int wave = tid >> 6, lane = tid & 63;
  int p = lane & 15, q = lane >> 4;
  int rowbase = blockIdx.x * (64 * MT) + wave * (16 * MT);

  int rcl[MT];  // A-load row per m-tile (clamped in-bounds)
#pragma unroll
  for (int m = 0; m < MT; ++m) rcl[m] = min(rowbase + m * 16 + p, n - 1);

  float4v acc[MT][NCT];
#pragma unroll
  for (int m = 0; m < MT; ++m)
#pragma unroll
    for (int t = 0; t < NCT; ++t) acc[m][t] = (float4v){0.f, 0.f, 0.f, 0.f};

#pragma unroll
  for (int kt = 0; kt < KT; ++kt) {
    const bool seg0 = (kt < K0T);  // compile-time after unroll
    const void* ab = seg0 ? A0 : A1;
    const int lda = seg0 ? lda0 : lda1;
    const int kof = (seg0 ? kt : (kt - K0T)) * 32;
    const int at = seg0 ? A0T : A1T;
    short8 af[MT];
#pragma unroll
    for (int m = 0; m < MT; ++m) {
      long long base = (long long)rcl[m] * lda + kof + q * 8;
      if (at == AT_BF16) {
        af[m] = *(const short8*)((const bf16*)ab + base);
      } else {
        const float* fb = (const float*)ab + base;
        float4 a = *(const float4*)fb;
        float4 b = *(const float4*)(fb + 4);
        short8 r;
        r[0] = (short)f2bu(a.x); r[1] = (short)f2bu(a.y);
        r[2] = (short)f2bu(a.z); r[3] = (short)f2bu(a.w);
        r[4] = (short)f2bu(b.x); r[5] = (short)f2bu(b.y);
        r[6] = (short)f2bu(b.z); r[7] = (short)f2bu(b.w);
        af[m] = r;
      }
    }
#pragma unroll
    for (int t = 0; t < NCT; ++t) {
      int c = t * 16 + p;
      short8 bfr = *(const short8*)(Wt + (long long)c * K + kt * 32 + q * 8);
#pragma unroll
      for (int m = 0; m < MT; ++m)
        acc[m][t] = __builtin_amdgcn_mfma_f32_16x16x32_bf16(af[m], bfr, acc[m][t], 0, 0, 0);
    }
  }

#pragma unroll
  for (int m = 0; m < MT; ++m) {
#pragma unroll
    for (int t = 0; t < NCT; ++t) {
      int c = t * 16 + p;
      float bv = bias[c];
#pragma unroll
      for (int r = 0; r < 4; ++r) {
        int row = rowbase + m * 16 + q * 4 + r;
        if (row < n) {
          float v = acc[m][t][r] + bv;
          if (relu) v = fmaxf(v, 0.f);
          long long idx = cbase + (long long)row * ldc + c;
          if (OUTF32) ((float*)C)[idx] = v;
          else        ((bf16*)C)[idx] = __float2bfloat16(v);
        }
      }
    }
  }
}

// ======================= host ================================================
extern "C" void kernel_launch(void* const* d_in, const int* in_sizes, int n_in,
                              void* d_out, int out_size, void* d_ws,
                              size_t ws_size, hipStream_t stream) {
  const float* x_txn = (const float*)d_in[0];
  const float* x_cli = (const float*)d_in[1];
  const int* ct_src = (const int*)d_in[2];
  const int* ct_dst = (const int*)d_in[3];
  const int* tc_src = (const int*)d_in[4];
  const int* tc_dst = (const int*)d_in[5];
  const float* W1ctl = (const float*)d_in[6];
  const float* b1ct  = (const float*)d_in[7];
  const float* W1ctr = (const float*)d_in[8];
  const float* W1tcl = (const float*)d_in[9];
  const float* b1tc  = (const float*)d_in[10];
  const float* W1tcr = (const float*)d_in[11];
  const float* W2ctl = (const float*)d_in[12];
  const float* b2ct  = (const float*)d_in[13];
  const float* W2ctr = (const float*)d_in[14];
  const float* W2tcl = (const float*)d_in[15];
  const float* b2tc  = (const float*)d_in[16];
  const float* W2tcr = (const float*)d_in[17];
  const float* Wd1   = (const float*)d_in[18];
  const float* bd1   = (const float*)d_in[19];
  const float* Wd2   = (const float*)d_in[20];
  const float* bd2   = (const float*)d_in[21];

  const int E = in_sizes[2];  // 600000
  const int NT = 100000, NC = 20000;
  const int NBK_CT = (NT + 255) >> 8;  // 391
  const int NBK_TC = (NC + 255) >> 8;  // 79

  // ---- workspace carve: ~85.5 MB (< 92.64 MB proven bound) ----
  size_t o = 0;
  auto carve = [&](size_t bytes) {
    void* p = (char*)d_ws + o;
    o = (o + bytes + 255) & ~(size_t)255;
    return p;
  };
  int* bcnt_ct = (int*)carve((size_t)NBK_CT * 4);       // zeroed
  int* bcnt_tc = (int*)carve((size_t)NBK_TC * 4);       // zeroed (same page run)
  size_t zero_bytes = o;
  int* boff_ct = (int*)carve((size_t)(NBK_CT + 1) * 4);
  int* boff_tc = (int*)carve((size_t)(NBK_TC + 1) * 4);
  int* bcur_ct = (int*)carve((size_t)NBK_CT * 4);
  int* bcur_tc = (int*)carve((size_t)NBK_TC * 4);
  uint2* se_ct = (uint2*)carve((size_t)E * 8);
  uint2* se_tc = (uint2*)carve((size_t)E * 8);
  int* off_ct = (int*)carve((size_t)(NT + 1) * 4);
  int* off_tc = (int*)carve((size_t)(NC + 1) * 4);
  int* csr_ct = (int*)carve((size_t)E * 4);
  int* csr_tc = (int*)carve((size_t)E * 4);
  ushort* Wt1 = (ushort*)carve((size_t)96 * 128 * 2);
  ushort* Wt2 = (ushort*)carve((size_t)96 * 128 * 2);
  ushort* Wt3 = (ushort*)carve((size_t)256 * 128 * 2);
  ushort* Wt4 = (ushort*)carve((size_t)256 * 128 * 2);
  ushort* Wt5 = (ushort*)carve((size_t)128 * 64 * 2);
  ushort* Wt6 = (ushort*)carve((size_t)64 * 64 * 2);
  bf16* mean1_ct = (bf16*)carve((size_t)NT * 32 * 2);
  bf16* mean1_tc = (bf16*)carve((size_t)NC * 64 * 2);
  bf16* h_txn    = (bf16*)carve((size_t)NT * 128 * 2);
  bf16* h_cli    = (bf16*)carve((size_t)NC * 128 * 2);
  bf16* mean2_ct = (bf16*)carve((size_t)NT * 128 * 2);
  bf16* mean2_tc = (bf16*)carve((size_t)NC * 128 * 2);
  bf16* dec_t = mean2_ct;  // dead by decoder time (12.8 MB <= 25.6 MB)
  (void)ws_size;

  hipMemsetAsync(d_ws, 0, zero_bytes, stream);

  const int tb = 256;
  const int CH = (E + 4095) / 4096;  // 147 chunks per edge type

  // ---- fused weight transposes (1 launch) ----
  {
    TJobs js;
    auto blocks = [](int k, int ncol) { return (k * ncol + 255) / 256; };
    int boff = 0;
    auto setj = [&](int idx, const float* wl, const float* wr, ushort* dst,
                    int da, int k, int ncol) {
      js.j[idx] = TJob{wl, wr, dst, da, k, ncol, boff};
      boff += blocks(k, ncol);
    };
    setj(0, W1ctl, W1ctr, Wt1, 32, 96, 128);
    setj(1, W1tcl, W1tcr, Wt2, 64, 96, 128);
    setj(2, W2ctl, W2ctr, Wt3, 128, 256, 128);
    setj(3, W2tcl, W2tcr, Wt4, 128, 256, 128);
    setj(4, Wd1, Wd1, Wt5, 128, 128, 64);
    setj(5, Wd2, Wd2, Wt6, 64, 64, 64);
    transpose6_kernel<<<boff, tb, 0, stream>>>(js);
  }

  // ---- CSR build: two-level counting sort (both edge types fused) ----
  bhist_kernel<<<2 * CH, tb, 0, stream>>>(ct_dst, bcnt_ct, NBK_CT,
                                          tc_dst, bcnt_tc, NBK_TC, E, CH);
  bscan_kernel<<<2, 512, 0, stream>>>(bcnt_ct, boff_ct, bcur_ct, NBK_CT,
                                      bcnt_tc, boff_tc, bcur_tc, NBK_TC);
  multisplit_kernel<<<2 * CH, tb, 0, stream>>>(
      ct_src, ct_dst, bcur_ct, se_ct, NBK_CT,
      tc_src, tc_dst, bcur_tc, se_tc, NBK_TC, E, CH);
  csr_fine_kernel<<<NBK_CT + NBK_TC, tb, 0, stream>>>(
      se_ct, boff_ct, off_ct, csr_ct, NT, NBK_CT,
      se_tc, boff_tc, off_tc, csr_tc, NC);

  auto gbm = [](int n, int mt) { return (n + 64 * mt - 1) / (64 * mt); };

  // ---- layer 1: pull means (fp32 inputs) then fused linears ----
  pull_mean_kernel<32, false><<<(NT + 3) / 4, tb, 0, stream>>>(
      off_ct, csr_ct, x_cli, mean1_ct, NT, NC);
  pull_mean_kernel<64, false><<<(NC + 3) / 4, tb, 0, stream>>>(
      off_tc, csr_tc, x_txn, mean1_tc, NC, NT);

  gemm_kernel<3, 8, 1, AT_BF16, AT_F32, false, 4><<<gbm(NT, 4), tb, 0, stream>>>(
      mean1_ct, 32, x_txn, 64, Wt1, b1ct, h_txn, 0, 128, NT, 1);
  gemm_kernel<3, 8, 2, AT_BF16, AT_F32, false, 1><<<gbm(NC, 1), tb, 0, stream>>>(
      mean1_tc, 64, x_cli, 32, Wt2, b1tc, h_cli, 0, 128, NC, 1);

  // ---- layer 2: pull means (bf16 h) then fused linears ----
  pull_mean_kernel<128, true><<<(NT + 3) / 4, tb, 0, stream>>>(
      off_ct, csr_ct, h_cli, mean2_ct, NT, NC);
  pull_mean_kernel<128, true><<<(NC + 3) / 4, tb, 0, stream>>>(
      off_tc, csr_tc, h_txn, mean2_tc, NC, NT);

  float* out = (float*)d_out;
  const long long ztxn_base = (long long)NT * 64;
  const long long zcli_base = ztxn_base + (long long)NT * 128;

  gemm_kernel<8, 8, 4, AT_BF16, AT_BF16, true, 4><<<gbm(NT, 4), tb, 0, stream>>>(
      mean2_ct, 128, h_txn, 128, Wt3, b2ct, out, ztxn_base, 128, NT, 0);
  gemm_kernel<8, 8, 4, AT_BF16, AT_BF16, true, 1><<<gbm(NC, 1), tb, 0, stream>>>(
      mean2_tc, 128, h_cli, 128, Wt4, b2tc, out, zcli_base, 128, NC, 0);

  // ---- decoder: recon = relu(z @ Wd1 + b) @ Wd2 + b  (z fp32 in d_out) ----
  gemm_kernel<4, 4, 4, AT_F32, AT_F32, false, 4><<<gbm(NT, 4), tb, 0, stream>>>(
      out + ztxn_base, 128, out + ztxn_base, 128, Wt5, bd1, dec_t, 0, 64, NT, 1);
  gemm_kernel<2, 4, 2, AT_BF16, AT_BF16, true, 4><<<gbm(NT, 4), tb, 0, stream>>>(
      dec_t, 64, dec_t, 64, Wt6, bd2, out, 0, 64, NT, 0);
}

// Round 2
// 413.877 us; speedup vs baseline: 1.1603x; 1.0548x over previous
//
#include <hip/hip_runtime.h>
#include <hip/hip_bf16.h>

typedef __hip_bfloat16 bf16;
typedef unsigned int uint;
typedef unsigned short ushort;
typedef __attribute__((ext_vector_type(8))) short short8;   // 8 bf16 = 4 VGPR
typedef __attribute__((ext_vector_type(4))) float float4v;  // MFMA acc

__device__ __forceinline__ float lo2f(uint v) { return __uint_as_float(v << 16); }
__device__ __forceinline__ float hi2f(uint v) { return __uint_as_float(v & 0xffff0000u); }
__device__ __forceinline__ ushort f2bu(float v) {
  union { bf16 h; ushort u; } x;
  x.h = __float2bfloat16(v);
  return x.u;
}
__device__ __forceinline__ uint packbf2(float a, float b) {
  return (uint)f2bu(a) | ((uint)f2bu(b) << 16);
}

#define BSH 8          // bucket shift: 256 nodes per bucket
#define NBK_MAX 391    // max buckets (txn side)

// ======================= fused weight transpose (6 jobs, 1 launch) ===========
struct TJob { const float* wl; const float* wr; ushort* dst; int da, k, ncol, boff; };
struct TJobs { TJob j[6]; };

__global__ void transpose6_kernel(TJobs js) {
  int b = blockIdx.x;
  int jj = 0;
#pragma unroll
  for (int t = 1; t < 6; ++t)
    if (b >= js.j[t].boff) jj = t;
  const TJob J = js.j[jj];
  int i = (b - J.boff) * 256 + threadIdx.x;
  if (i >= J.k * J.ncol) return;
  int k = i / J.ncol, c = i - k * J.ncol;
  const float* srcp = (k < J.da) ? (J.wl + (long long)k * J.ncol)
                                 : (J.wr + (long long)(k - J.da) * J.ncol);
  J.dst[(long long)c * J.k + k] = f2bu(srcp[c]);
}

// ======================= CSR build, two-level counting sort ==================
// Phase 1: coarse histogram of dst>>BSH (LDS per block, atomic merge).
__global__ void bhist_kernel(const int* __restrict__ dA, int* __restrict__ cA, int nbkA,
                             const int* __restrict__ dB, int* __restrict__ cB, int nbkB,
                             int E, int chA) {
  __shared__ int h[NBK_MAX];
  int b = blockIdx.x;
  const int* dst; int* gc; int nbk;
  if (b < chA) { dst = dA; gc = cA; nbk = nbkA; }
  else         { b -= chA; dst = dB; gc = cB; nbk = nbkB; }
  for (int i = threadIdx.x; i < nbk; i += 256) h[i] = 0;
  __syncthreads();
  int e0 = b * 4096;
  for (int j = 0; j < 16; ++j) {
    int e = e0 + j * 256 + threadIdx.x;
    if (e < E) {
      uint B = (uint)dst[e] >> BSH;
      if (B < (uint)nbk) atomicAdd(&h[B], 1);
    }
  }
  __syncthreads();
  for (int i = threadIdx.x; i < nbk; i += 256)
    if (h[i]) atomicAdd(&gc[i], h[i]);
}

// Phase 2: exclusive scan of bucket counts -> bucket offsets + cursors.
__global__ void bscan_kernel(const int* __restrict__ cA, int* __restrict__ oA,
                             int* __restrict__ uA, int nbkA,
                             const int* __restrict__ cB, int* __restrict__ oB,
                             int* __restrict__ uB, int nbkB) {
  __shared__ int s[512];
  const int* cnt; int* off; int* cur; int nbk;
  if (blockIdx.x == 0) { cnt = cA; off = oA; cur = uA; nbk = nbkA; }
  else                 { cnt = cB; off = oB; cur = uB; nbk = nbkB; }
  int t = threadIdx.x;
  int v = (t < nbk) ? cnt[t] : 0;
  s[t] = v;
  __syncthreads();
  for (int o = 1; o < 512; o <<= 1) {
    int x = (t >= o) ? s[t - o] : 0;
    __syncthreads();
    s[t] += x;
    __syncthreads();
  }
  if (t < nbk) { int ex = s[t] - v; off[t] = ex; cur[t] = ex; }
  if (t == nbk - 1) off[nbk] = s[t];
}

// Phase 3: multisplit — scatter (src,dst) into bucket-sorted uint2 array.
// Per-block LDS ranking => per (block,bucket) contiguous write runs.
__global__ void multisplit_kernel(const int* __restrict__ sA, const int* __restrict__ dA,
                                  int* __restrict__ uA, uint2* __restrict__ seA, int nbkA,
                                  const int* __restrict__ sB, const int* __restrict__ dB,
                                  int* __restrict__ uB, uint2* __restrict__ seB, int nbkB,
                                  int E, int chA) {
  __shared__ int cnt[NBK_MAX];
  __shared__ int base[NBK_MAX];
  int b = blockIdx.x;
  const int *src, *dst; int* gcur; uint2* se; int nbk;
  if (b < chA) { src = sA; dst = dA; gcur = uA; se = seA; nbk = nbkA; }
  else         { b -= chA; src = sB; dst = dB; gcur = uB; se = seB; nbk = nbkB; }
  for (int i = threadIdx.x; i < nbk; i += 256) cnt[i] = 0;
  __syncthreads();
  int e0 = b * 4096;
  int mys[16], myd[16], myb[16], myr[16];
#pragma unroll
  for (int j = 0; j < 16; ++j) {
    int e = e0 + j * 256 + threadIdx.x;
    int s = 0, d = 0, bb = -1, r = 0;
    if (e < E) {
      s = src[e]; d = dst[e];
      uint B = (uint)d >> BSH;
      if (B < (uint)nbk) { bb = (int)B; r = atomicAdd(&cnt[bb], 1); }
    }
    mys[j] = s; myd[j] = d; myb[j] = bb; myr[j] = r;
  }
  __syncthreads();
  for (int i = threadIdx.x; i < nbk; i += 256) {
    int c = cnt[i];
    base[i] = c ? atomicAdd(&gcur[i], c) : 0;
  }
  __syncthreads();
#pragma unroll
  for (int j = 0; j < 16; ++j) {
    if (myb[j] >= 0) {
      uint2 v; v.x = (uint)mys[j]; v.y = (uint)myd[j];
      se[base[myb[j]] + myr[j]] = v;
    }
  }
}

// Phase 4: per-bucket fine CSR — one block per bucket, all ranking in LDS.
__global__ void csr_fine_kernel(const uint2* __restrict__ seA, const int* __restrict__ boA,
                                int* __restrict__ offA, int* __restrict__ csrA, int nA, int nbkA,
                                const uint2* __restrict__ seB, const int* __restrict__ boB,
                                int* __restrict__ offB, int* __restrict__ csrB, int nB) {
  __shared__ int s[256];
  __shared__ int cur[256];
  int b = blockIdx.x;
  const uint2* se; const int* bo; int* off; int* csr; int n;
  if (b < nbkA) { se = seA; bo = boA; off = offA; csr = csrA; n = nA; }
  else          { b -= nbkA; se = seB; bo = boB; off = offB; csr = csrB; n = nB; }
  int t = threadIdx.x;
  int ebeg = bo[b], eend = bo[b + 1];
  // local degree histogram
  cur[t] = 0;
  __syncthreads();
  for (int i = ebeg + t; i < eend; i += 256)
    atomicAdd(&cur[se[i].y & 255], 1);
  __syncthreads();
  int v = cur[t];
  s[t] = v;
  __syncthreads();
  for (int o = 1; o < 256; o <<= 1) {
    int x = (t >= o) ? s[t - o] : 0;
    __syncthreads();
    s[t] += x;
    __syncthreads();
  }
  int excl = s[t] - v;
  int node = b * 256 + t;
  if (node < n) off[node] = ebeg + excl;
  if (node == n - 1) off[n] = ebeg + excl + v;
  cur[t] = excl;
  __syncthreads();
  for (int i = ebeg + t; i < eend; i += 256) {
    uint2 e = se[i];
    int pos = ebeg + atomicAdd(&cur[e.y & 255], 1);
    csr[pos] = (int)e.x;
  }
}

// ======================= pull aggregation (mean, bf16 out) — R8-validated ====
template <int D, bool XBF>
__global__ __launch_bounds__(256) void pull_mean_kernel(
    const int* __restrict__ off, const int* __restrict__ csr,
    const void* __restrict__ x, bf16* __restrict__ mean, int n, int nsrc) {
  constexpr int LPR = D / 4;          // lanes per row (4 elems per lane)
  constexpr int PAR = 64 / LPR;       // edges in parallel
  int node = blockIdx.x * 4 + (threadIdx.x >> 6);
  if (node >= n) return;  // wave-uniform
  int lane = threadIdx.x & 63;
  int h = lane / LPR, col = lane % LPR;
  int beg = off[node], deg = off[node + 1] - beg;
  float inv = 1.0f / fmaxf((float)deg, 1.0f);
  float a0 = 0.f, a1 = 0.f, a2 = 0.f, a3 = 0.f;
  for (int i = h; i < deg; i += PAR) {
    int s = csr[beg + i];
    s = ((unsigned)s < (unsigned)nsrc) ? s : 0;
    if (XBF) {
      uint2 v = ((const uint2*)x)[(long long)s * LPR + col];
      a0 += lo2f(v.x); a1 += hi2f(v.x); a2 += lo2f(v.y); a3 += hi2f(v.y);
    } else {
      float4 v = ((const float4*)x)[(long long)s * LPR + col];
      a0 += v.x; a1 += v.y; a2 += v.z; a3 += v.w;
    }
  }
#pragma unroll
  for (int m = LPR; m < 64; m <<= 1) {
    a0 += __shfl_xor(a0, m); a1 += __shfl_xor(a1, m);
    a2 += __shfl_xor(a2, m); a3 += __shfl_xor(a3, m);
  }
  if (h == 0) {
    uint2 o2;
    o2.x = packbf2(a0 * inv, a1 * inv);
    o2.y = packbf2(a2 * inv, a3 * inv);
    ((uint2*)mean)[(long long)node * LPR + col] = o2;
  }
}

// ======================= MFMA GEMM (no LDS, branch-free, MT row-tiles) =======
// MT = 16-row M-tiles per wave. B fragments loaded once per (kt,t), reused
// across MT MFMAs (R1-validated: fixed the 78us latency wall).
#define AT_BF16 0
#define AT_F32  1
template <int KT, int NCT, int K0T, int A0T, int A1T, bool OUTF32, int MT>
__global__ __launch_bounds__(256, 2) void gemm_kernel(
    const void* __restrict__ A0, int lda0,
    const void* __restrict__ A1, int lda1,
    const ushort* __restrict__ Wt, const float* __restrict__ bias,
    void* __restrict__ C, long long cbase, int ldc, int n, int relu) {
  constexpr int K = KT * 32;
  int tid = threadIdx.x;
  int wave = tid >> 6, lane = tid & 63;
  int p = lane & 15, q = lane >> 4;
  int rowbase = blockIdx.x * (64 * MT) + wave * (16 * MT);

  int rcl[MT];  // A-load row per m-tile (clamped in-bounds)
#pragma unroll
  for (int m = 0; m < MT; ++m) rcl[m] = min(rowbase + m * 16 + p, n - 1);

  float4v acc[MT][NCT];
#pragma unroll
  for (int m = 0; m < MT; ++m)
#pragma unroll
    for (int t = 0; t < NCT; ++t) acc[m][t] = (float4v){0.f, 0.f, 0.f, 0.f};

#pragma unroll
  for (int kt = 0; kt < KT; ++kt) {
    const bool seg0 = (kt < K0T);  // compile-time after unroll
    const void* ab = seg0 ? A0 : A1;
    const int lda = seg0 ? lda0 : lda1;
    const int kof = (seg0 ? kt : (kt - K0T)) * 32;
    const int at = seg0 ? A0T : A1T;
    short8 af[MT];
#pragma unroll
    for (int m = 0; m < MT; ++m) {
      long long base = (long long)rcl[m] * lda + kof + q * 8;
      if (at == AT_BF16) {
        af[m] = *(const short8*)((const bf16*)ab + base);
      } else {
        const float* fb = (const float*)ab + base;
        float4 a = *(const float4*)fb;
        float4 b = *(const float4*)(fb + 4);
        short8 r;
        r[0] = (short)f2bu(a.x); r[1] = (short)f2bu(a.y);
        r[2] = (short)f2bu(a.z); r[3] = (short)f2bu(a.w);
        r[4] = (short)f2bu(b.x); r[5] = (short)f2bu(b.y);
        r[6] = (short)f2bu(b.z); r[7] = (short)f2bu(b.w);
        af[m] = r;
      }
    }
#pragma unroll
    for (int t = 0; t < NCT; ++t) {
      int c = t * 16 + p;
      short8 bfr = *(const short8*)(Wt + (long long)c * K + kt * 32 + q * 8);
#pragma unroll
      for (int m = 0; m < MT; ++m)
        acc[m][t] = __builtin_amdgcn_mfma_f32_16x16x32_bf16(af[m], bfr, acc[m][t], 0, 0, 0);
    }
  }

#pragma unroll
  for (int m = 0; m < MT; ++m) {
#pragma unroll
    for (int t = 0; t < NCT; ++t) {
      int c = t * 16 + p;
      float bv = bias[c];
#pragma unroll
      for (int r = 0; r < 4; ++r) {
        int row = rowbase + m * 16 + q * 4 + r;
        if (row < n) {
          float v = acc[m][t][r] + bv;
          if (relu) v = fmaxf(v, 0.f);
          long long idx = cbase + (long long)row * ldc + c;
          if (OUTF32) ((float*)C)[idx] = v;
          else        ((bf16*)C)[idx] = __float2bfloat16(v);
        }
      }
    }
  }
}

// ======================= fused L2-txn GEMM + decoder =========================
// z = [mean2_ct|h_txn] @ W2ct + b2   (K=256, 128 cols, f32 -> d_out z-slab)
// d1 = relu(z @ Wd1 + bd1)            (in-register via LDS round-trip)
// recon = d1 @ Wd2 + bd2              (f32 -> d_out recon-slab)
// Trick: swapped MFMA operands (mfma(Wfrag, Afrag, acc)) give z TRANSPOSED in
// regs: lane p = row, regs = 4 consecutive cols -> one ds_write_b64 per (m,t)
// into a wave-private XOR-swizzled LDS tile, read back as A-fragments
// (ds_read_b128) for the decoder MFMA stages. All numerics identical to the
// unfused 3-kernel chain (same f32->bf16 rounding points, same k-order).
__global__ __launch_bounds__(256, 2) void gemm_fused_dec_kernel(
    const bf16* __restrict__ A0,   // mean2_ct [n][128]
    const bf16* __restrict__ A1,   // h_txn    [n][128]
    const ushort* __restrict__ W3, // Wt3 [128][256]
    const float* __restrict__ b2,  // [128]
    const ushort* __restrict__ W5, // Wt5 [64][128]
    const float* __restrict__ bd1v,// [64]
    const ushort* __restrict__ W6, // Wt6 [64][64]
    const float* __restrict__ bd2v,// [64]
    float* __restrict__ zout,      // d_out + ztxn_base, ld 128
    float* __restrict__ recon,     // d_out, ld 64
    int n) {
  __shared__ __align__(16) char zls[65536];  // 4 waves x 16KB, wave-private
  int tid = threadIdx.x;
  int wave = tid >> 6, lane = tid & 63;
  int p = lane & 15, q = lane >> 4;
  int rowbase = blockIdx.x * 256 + wave * 64;
  char* wls = zls + wave * 16384;
  const int sw = (p & 7) << 4;  // XOR swizzle: rows stride 256B/128B -> 2-way banks

  int rcl[4];
#pragma unroll
  for (int m = 0; m < 4; ++m) rcl[m] = min(rowbase + m * 16 + p, n - 1);

  // ---- stage 1: z accumulators (transposed layout) ----
  float4v accz[4][8];
#pragma unroll
  for (int m = 0; m < 4; ++m)
#pragma unroll
    for (int t = 0; t < 8; ++t) accz[m][t] = (float4v){0.f, 0.f, 0.f, 0.f};

#pragma unroll
  for (int kt = 0; kt < 8; ++kt) {
    const bf16* ab = (kt < 4) ? A0 : A1;
    const int kof = (kt & 3) * 32;
    short8 af[4];
#pragma unroll
    for (int m = 0; m < 4; ++m)
      af[m] = *(const short8*)(ab + (long long)rcl[m] * 128 + kof + q * 8);
#pragma unroll
    for (int t = 0; t < 8; ++t) {
      short8 bfr = *(const short8*)(W3 + (long long)(t * 16 + p) * 256 + kt * 32 + q * 8);
#pragma unroll
      for (int m = 0; m < 4; ++m)  // swapped: D[i=col][j=row] => z^T layout
        accz[m][t] = __builtin_amdgcn_mfma_f32_16x16x32_bf16(bfr, af[m], accz[m][t], 0, 0, 0);
    }
  }

  // epilogue: z -> global f32 (+bias), z -> LDS bf16 (row-major [64][256B], swz)
#pragma unroll
  for (int m = 0; m < 4; ++m) {
    int lr = m * 16 + p;           // local row
    int row = rowbase + lr;
#pragma unroll
    for (int t = 0; t < 8; ++t) {
      float4v bz = *(const float4v*)(b2 + t * 16 + q * 4);
      float4v v;
#pragma unroll
      for (int r = 0; r < 4; ++r) v[r] = accz[m][t][r] + bz[r];
      if (row < n)
        *(float4v*)(zout + (long long)row * 128 + t * 16 + q * 4) = v;
      uint2 u;
      u.x = packbf2(v[0], v[1]);
      u.y = packbf2(v[2], v[3]);
      *(uint2*)(wls + (((lr * 256 + t * 32 + q * 8)) ^ sw)) = u;
    }
  }
  __syncthreads();

  // ---- stage 2: d1 = relu(z @ Wd1 + bd1), K=128, 64 cols ----
  float4v accd[4][4];
#pragma unroll
  for (int m = 0; m < 4; ++m)
#pragma unroll
    for (int t = 0; t < 4; ++t) accd[m][t] = (float4v){0.f, 0.f, 0.f, 0.f};

#pragma unroll
  for (int kt2 = 0; kt2 < 4; ++kt2) {
    short8 zf[4];
#pragma unroll
    for (int m = 0; m < 4; ++m)
      zf[m] = *(const short8*)(wls + (((m * 16 + p) * 256 + kt2 * 64 + q * 16) ^ sw));
#pragma unroll
    for (int t2 = 0; t2 < 4; ++t2) {
      short8 wf = *(const short8*)(W5 + (long long)(t2 * 16 + p) * 128 + kt2 * 32 + q * 8);
#pragma unroll
      for (int m = 0; m < 4; ++m)
        accd[m][t2] = __builtin_amdgcn_mfma_f32_16x16x32_bf16(wf, zf[m], accd[m][t2], 0, 0, 0);
    }
  }
  __syncthreads();  // all z-reads done before overwriting region with d1

  // d1 (relu, bf16) -> LDS row-major [64][128B], same swizzle
#pragma unroll
  for (int m = 0; m < 4; ++m) {
    int lr = m * 16 + p;
#pragma unroll
    for (int t2 = 0; t2 < 4; ++t2) {
      float4v bb = *(const float4v*)(bd1v + t2 * 16 + q * 4);
      float4v v;
#pragma unroll
      for (int r = 0; r < 4; ++r) v[r] = fmaxf(accd[m][t2][r] + bb[r], 0.f);
      uint2 u;
      u.x = packbf2(v[0], v[1]);
      u.y = packbf2(v[2], v[3]);
      *(uint2*)(wls + (((lr * 128 + t2 * 32 + q * 8)) ^ sw)) = u;
    }
  }
  // same-wave LDS write->read is in-order; no barrier needed

  // ---- stage 3: recon = d1 @ Wd2 + bd2, K=64, 64 cols ----
  float4v accr[4][4];
#pragma unroll
  for (int m = 0; m < 4; ++m)
#pragma unroll
    for (int t = 0; t < 4; ++t) accr[m][t] = (float4v){0.f, 0.f, 0.f, 0.f};

#pragma unroll
  for (int kt3 = 0; kt3 < 2; ++kt3) {
    short8 df[4];
#pragma unroll
    for (int m = 0; m < 4; ++m)
      df[m] = *(const short8*)(wls + (((m * 16 + p) * 128 + kt3 * 64 + q * 16) ^ sw));
#pragma unroll
    for (int t3 = 0; t3 < 4; ++t3) {
      short8 wf = *(const short8*)(W6 + (long long)(t3 * 16 + p) * 64 + kt3 * 32 + q * 8);
#pragma unroll
      for (int m = 0; m < 4; ++m)
        accr[m][t3] = __builtin_amdgcn_mfma_f32_16x16x32_bf16(wf, df[m], accr[m][t3], 0, 0, 0);
    }
  }

#pragma unroll
  for (int m = 0; m < 4; ++m) {
    int row = rowbase + m * 16 + p;
    if (row < n) {
#pragma unroll
      for (int t3 = 0; t3 < 4; ++t3) {
        float4v bb = *(const float4v*)(bd2v + t3 * 16 + q * 4);
        float4v v;
#pragma unroll
        for (int r = 0; r < 4; ++r) v[r] = accr[m][t3][r] + bb[r];
        *(float4v*)(recon + (long long)row * 64 + t3 * 16 + q * 4) = v;
      }
    }
  }
}

// ======================= host ================================================
extern "C" void kernel_launch(void* const* d_in, const int* in_sizes, int n_in,
                              void* d_out, int out_size, void* d_ws,
                              size_t ws_size, hipStream_t stream) {
  const float* x_txn = (const float*)d_in[0];
  const float* x_cli = (const float*)d_in[1];
  const int* ct_src = (const int*)d_in[2];
  const int* ct_dst = (const int*)d_in[3];
  const int* tc_src = (const int*)d_in[4];
  const int* tc_dst = (const int*)d_in[5];
  const float* W1ctl = (const float*)d_in[6];
  const float* b1ct  = (const float*)d_in[7];
  const float* W1ctr = (const float*)d_in[8];
  const float* W1tcl = (const float*)d_in[9];
  const float* b1tc  = (const float*)d_in[10];
  const float* W1tcr = (const float*)d_in[11];
  const float* W2ctl = (const float*)d_in[12];
  const float* b2ct  = (const float*)d_in[13];
  const float* W2ctr = (const float*)d_in[14];
  const float* W2tcl = (const float*)d_in[15];
  const float* b2tc  = (const float*)d_in[16];
  const float* W2tcr = (const float*)d_in[17];
  const float* Wd1   = (const float*)d_in[18];
  const float* bd1   = (const float*)d_in[19];
  const float* Wd2   = (const float*)d_in[20];
  const float* bd2   = (const float*)d_in[21];

  const int E = in_sizes[2];  // 600000
  const int NT = 100000, NC = 20000;
  const int NBK_CT = (NT + 255) >> 8;  // 391
  const int NBK_TC = (NC + 255) >> 8;  // 79

  // ---- workspace carve ----
  size_t o = 0;
  auto carve = [&](size_t bytes) {
    void* p = (char*)d_ws + o;
    o = (o + bytes + 255) & ~(size_t)255;
    return p;
  };
  int* bcnt_ct = (int*)carve((size_t)NBK_CT * 4);       // zeroed
  int* bcnt_tc = (int*)carve((size_t)NBK_TC * 4);       // zeroed (same page run)
  size_t zero_bytes = o;
  int* boff_ct = (int*)carve((size_t)(NBK_CT + 1) * 4);
  int* boff_tc = (int*)carve((size_t)(NBK_TC + 1) * 4);
  int* bcur_ct = (int*)carve((size_t)NBK_CT * 4);
  int* bcur_tc = (int*)carve((size_t)NBK_TC * 4);
  uint2* se_ct = (uint2*)carve((size_t)E * 8);
  uint2* se_tc = (uint2*)carve((size_t)E * 8);
  int* off_ct = (int*)carve((size_t)(NT + 1) * 4);
  int* off_tc = (int*)carve((size_t)(NC + 1) * 4);
  int* csr_ct = (int*)carve((size_t)E * 4);
  int* csr_tc = (int*)carve((size_t)E * 4);
  ushort* Wt1 = (ushort*)carve((size_t)96 * 128 * 2);
  ushort* Wt2 = (ushort*)carve((size_t)96 * 128 * 2);
  ushort* Wt3 = (ushort*)carve((size_t)256 * 128 * 2);
  ushort* Wt4 = (ushort*)carve((size_t)256 * 128 * 2);
  ushort* Wt5 = (ushort*)carve((size_t)128 * 64 * 2);
  ushort* Wt6 = (ushort*)carve((size_t)64 * 64 * 2);
  bf16* mean1_ct = (bf16*)carve((size_t)NT * 32 * 2);
  bf16* mean1_tc = (bf16*)carve((size_t)NC * 64 * 2);
  bf16* h_txn    = (bf16*)carve((size_t)NT * 128 * 2);
  bf16* h_cli    = (bf16*)carve((size_t)NC * 128 * 2);
  bf16* mean2_ct = (bf16*)carve((size_t)NT * 128 * 2);
  bf16* mean2_tc = (bf16*)carve((size_t)NC * 128 * 2);
  (void)ws_size;

  hipMemsetAsync(d_ws, 0, zero_bytes, stream);

  const int tb = 256;
  const int CH = (E + 4095) / 4096;  // 147 chunks per edge type

  // ---- fused weight transposes (1 launch) ----
  {
    TJobs js;
    auto blocks = [](int k, int ncol) { return (k * ncol + 255) / 256; };
    int boff = 0;
    auto setj = [&](int idx, const float* wl, const float* wr, ushort* dst,
                    int da, int k, int ncol) {
      js.j[idx] = TJob{wl, wr, dst, da, k, ncol, boff};
      boff += blocks(k, ncol);
    };
    setj(0, W1ctl, W1ctr, Wt1, 32, 96, 128);
    setj(1, W1tcl, W1tcr, Wt2, 64, 96, 128);
    setj(2, W2ctl, W2ctr, Wt3, 128, 256, 128);
    setj(3, W2tcl, W2tcr, Wt4, 128, 256, 128);
    setj(4, Wd1, Wd1, Wt5, 128, 128, 64);
    setj(5, Wd2, Wd2, Wt6, 64, 64, 64);
    transpose6_kernel<<<boff, tb, 0, stream>>>(js);
  }

  // ---- CSR build: two-level counting sort (both edge types fused) ----
  bhist_kernel<<<2 * CH, tb, 0, stream>>>(ct_dst, bcnt_ct, NBK_CT,
                                          tc_dst, bcnt_tc, NBK_TC, E, CH);
  bscan_kernel<<<2, 512, 0, stream>>>(bcnt_ct, boff_ct, bcur_ct, NBK_CT,
                                      bcnt_tc, boff_tc, bcur_tc, NBK_TC);
  multisplit_kernel<<<2 * CH, tb, 0, stream>>>(
      ct_src, ct_dst, bcur_ct, se_ct, NBK_CT,
      tc_src, tc_dst, bcur_tc, se_tc, NBK_TC, E, CH);
  csr_fine_kernel<<<NBK_CT + NBK_TC, tb, 0, stream>>>(
      se_ct, boff_ct, off_ct, csr_ct, NT, NBK_CT,
      se_tc, boff_tc, off_tc, csr_tc, NC);

  auto gbm = [](int n, int mt) { return (n + 64 * mt - 1) / (64 * mt); };

  // ---- layer 1: pull means (fp32 inputs) then fused linears ----
  pull_mean_kernel<32, false><<<(NT + 3) / 4, tb, 0, stream>>>(
      off_ct, csr_ct, x_cli, mean1_ct, NT, NC);
  pull_mean_kernel<64, false><<<(NC + 3) / 4, tb, 0, stream>>>(
      off_tc, csr_tc, x_txn, mean1_tc, NC, NT);

  gemm_kernel<3, 8, 1, AT_BF16, AT_F32, false, 4><<<gbm(NT, 4), tb, 0, stream>>>(
      mean1_ct, 32, x_txn, 64, Wt1, b1ct, h_txn, 0, 128, NT, 1);
  gemm_kernel<3, 8, 2, AT_BF16, AT_F32, false, 1><<<gbm(NC, 1), tb, 0, stream>>>(
      mean1_tc, 64, x_cli, 32, Wt2, b1tc, h_cli, 0, 128, NC, 1);

  // ---- layer 2: pull means (bf16 h) ----
  pull_mean_kernel<128, true><<<(NT + 3) / 4, tb, 0, stream>>>(
      off_ct, csr_ct, h_cli, mean2_ct, NT, NC);
  pull_mean_kernel<128, true><<<(NC + 3) / 4, tb, 0, stream>>>(
      off_tc, csr_tc, h_txn, mean2_tc, NC, NT);

  float* out = (float*)d_out;
  const long long ztxn_base = (long long)NT * 64;
  const long long zcli_base = ztxn_base + (long long)NT * 128;

  // ---- fused: z_txn + decoder (replaces 3 kernels) ----
  gemm_fused_dec_kernel<<<gbm(NT, 4), tb, 0, stream>>>(
      mean2_ct, h_txn, Wt3, b2ct, Wt5, bd1, Wt6, bd2,
      out + ztxn_base, out, NT);

  gemm_kernel<8, 8, 4, AT_BF16, AT_BF16, true, 1><<<gbm(NC, 1), tb, 0, stream>>>(
      mean2_tc, 128, h_cli, 128, Wt4, b2tc, out, zcli_base, 128, NC, 0);
}

// Round 3
// 384.121 us; speedup vs baseline: 1.2502x; 1.0775x over previous
//
#include <hip/hip_runtime.h>
#include <hip/hip_bf16.h>

typedef __hip_bfloat16 bf16;
typedef unsigned int uint;
typedef unsigned short ushort;
typedef __attribute__((ext_vector_type(8))) short short8;   // 8 bf16 = 4 VGPR
typedef __attribute__((ext_vector_type(4))) float float4v;  // MFMA acc

__device__ __forceinline__ float lo2f(uint v) { return __uint_as_float(v << 16); }
__device__ __forceinline__ float hi2f(uint v) { return __uint_as_float(v & 0xffff0000u); }
__device__ __forceinline__ ushort f2bu(float v) {
  union { bf16 h; ushort u; } x;
  x.h = __float2bfloat16(v);
  return x.u;
}
__device__ __forceinline__ uint packbf2(float a, float b) {
  return (uint)f2bu(a) | ((uint)f2bu(b) << 16);
}

#define BSH 8          // bucket shift: 256 nodes per bucket
#define NBK_MAX 391    // max buckets (txn side)

// ======================= fused weight transpose (6 jobs, 1 launch) ===========
struct TJob { const float* wl; const float* wr; ushort* dst; int da, k, ncol, boff; };
struct TJobs { TJob j[6]; };

__global__ void transpose6_kernel(TJobs js) {
  int b = blockIdx.x;
  int jj = 0;
#pragma unroll
  for (int t = 1; t < 6; ++t)
    if (b >= js.j[t].boff) jj = t;
  const TJob J = js.j[jj];
  int i = (b - J.boff) * 256 + threadIdx.x;
  if (i >= J.k * J.ncol) return;
  int k = i / J.ncol, c = i - k * J.ncol;
  const float* srcp = (k < J.da) ? (J.wl + (long long)k * J.ncol)
                                 : (J.wr + (long long)(k - J.da) * J.ncol);
  J.dst[(long long)c * J.k + k] = f2bu(srcp[c]);
}

// ======================= CSR build, two-level counting sort ==================
// Phase 1: coarse histogram of dst>>BSH (LDS per block, atomic merge).
__global__ void bhist_kernel(const int* __restrict__ dA, int* __restrict__ cA, int nbkA,
                             const int* __restrict__ dB, int* __restrict__ cB, int nbkB,
                             int E, int chA) {
  __shared__ int h[NBK_MAX];
  int b = blockIdx.x;
  const int* dst; int* gc; int nbk;
  if (b < chA) { dst = dA; gc = cA; nbk = nbkA; }
  else         { b -= chA; dst = dB; gc = cB; nbk = nbkB; }
  for (int i = threadIdx.x; i < nbk; i += 256) h[i] = 0;
  __syncthreads();
  int e0 = b * 4096;
  for (int j = 0; j < 16; ++j) {
    int e = e0 + j * 256 + threadIdx.x;
    if (e < E) {
      uint B = (uint)dst[e] >> BSH;
      if (B < (uint)nbk) atomicAdd(&h[B], 1);
    }
  }
  __syncthreads();
  for (int i = threadIdx.x; i < nbk; i += 256)
    if (h[i]) atomicAdd(&gc[i], h[i]);
}

// Phase 2: exclusive scan of bucket counts -> bucket offsets + cursors.
__global__ void bscan_kernel(const int* __restrict__ cA, int* __restrict__ oA,
                             int* __restrict__ uA, int nbkA,
                             const int* __restrict__ cB, int* __restrict__ oB,
                             int* __restrict__ uB, int nbkB) {
  __shared__ int s[512];
  const int* cnt; int* off; int* cur; int nbk;
  if (blockIdx.x == 0) { cnt = cA; off = oA; cur = uA; nbk = nbkA; }
  else                 { cnt = cB; off = oB; cur = uB; nbk = nbkB; }
  int t = threadIdx.x;
  int v = (t < nbk) ? cnt[t] : 0;
  s[t] = v;
  __syncthreads();
  for (int o = 1; o < 512; o <<= 1) {
    int x = (t >= o) ? s[t - o] : 0;
    __syncthreads();
    s[t] += x;
    __syncthreads();
  }
  if (t < nbk) { int ex = s[t] - v; off[t] = ex; cur[t] = ex; }
  if (t == nbk - 1) off[nbk] = s[t];
}

// Phase 3: multisplit — scatter (src,dst) into bucket-sorted uint2 array.
// Per-block LDS ranking => per (block,bucket) contiguous write runs.
__global__ void multisplit_kernel(const int* __restrict__ sA, const int* __restrict__ dA,
                                  int* __restrict__ uA, uint2* __restrict__ seA, int nbkA,
                                  const int* __restrict__ sB, const int* __restrict__ dB,
                                  int* __restrict__ uB, uint2* __restrict__ seB, int nbkB,
                                  int E, int chA) {
  __shared__ int cnt[NBK_MAX];
  __shared__ int base[NBK_MAX];
  int b = blockIdx.x;
  const int *src, *dst; int* gcur; uint2* se; int nbk;
  if (b < chA) { src = sA; dst = dA; gcur = uA; se = seA; nbk = nbkA; }
  else         { b -= chA; src = sB; dst = dB; gcur = uB; se = seB; nbk = nbkB; }
  for (int i = threadIdx.x; i < nbk; i += 256) cnt[i] = 0;
  __syncthreads();
  int e0 = b * 4096;
  int mys[16], myd[16], myb[16], myr[16];
#pragma unroll
  for (int j = 0; j < 16; ++j) {
    int e = e0 + j * 256 + threadIdx.x;
    int s = 0, d = 0, bb = -1, r = 0;
    if (e < E) {
      s = src[e]; d = dst[e];
      uint B = (uint)d >> BSH;
      if (B < (uint)nbk) { bb = (int)B; r = atomicAdd(&cnt[bb], 1); }
    }
    mys[j] = s; myd[j] = d; myb[j] = bb; myr[j] = r;
  }
  __syncthreads();
  for (int i = threadIdx.x; i < nbk; i += 256) {
    int c = cnt[i];
    base[i] = c ? atomicAdd(&gcur[i], c) : 0;
  }
  __syncthreads();
#pragma unroll
  for (int j = 0; j < 16; ++j) {
    if (myb[j] >= 0) {
      uint2 v; v.x = (uint)mys[j]; v.y = (uint)myd[j];
      se[base[myb[j]] + myr[j]] = v;
    }
  }
}

// Phase 4: per-bucket fine CSR — one block per bucket, all ranking in LDS.
__global__ void csr_fine_kernel(const uint2* __restrict__ seA, const int* __restrict__ boA,
                                int* __restrict__ offA, int* __restrict__ csrA, int nA, int nbkA,
                                const uint2* __restrict__ seB, const int* __restrict__ boB,
                                int* __restrict__ offB, int* __restrict__ csrB, int nB) {
  __shared__ int s[256];
  __shared__ int cur[256];
  int b = blockIdx.x;
  const uint2* se; const int* bo; int* off; int* csr; int n;
  if (b < nbkA) { se = seA; bo = boA; off = offA; csr = csrA; n = nA; }
  else          { b -= nbkA; se = seB; bo = boB; off = offB; csr = csrB; n = nB; }
  int t = threadIdx.x;
  int ebeg = bo[b], eend = bo[b + 1];
  // local degree histogram
  cur[t] = 0;
  __syncthreads();
  for (int i = ebeg + t; i < eend; i += 256)
    atomicAdd(&cur[se[i].y & 255], 1);
  __syncthreads();
  int v = cur[t];
  s[t] = v;
  __syncthreads();
  for (int o = 1; o < 256; o <<= 1) {
    int x = (t >= o) ? s[t - o] : 0;
    __syncthreads();
    s[t] += x;
    __syncthreads();
  }
  int excl = s[t] - v;
  int node = b * 256 + t;
  if (node < n) off[node] = ebeg + excl;
  if (node == n - 1) off[n] = ebeg + excl + v;
  cur[t] = excl;
  __syncthreads();
  for (int i = ebeg + t; i < eend; i += 256) {
    uint2 e = se[i];
    int pos = ebeg + atomicAdd(&cur[e.y & 255], 1);
    csr[pos] = (int)e.x;
  }
}

// ======================= pull aggregation (mean, bf16 out) ===================
// 16B/lane gathers (G13): bf16 rows as uint4 (8 bf16) -> LPR=D/8, PAR=64/LPR.
// For D=128 bf16 this doubles edges-in-flight (PAR 2->4), halving the
// sequential dependent-gather rounds that dominate high-degree nodes.
template <int D, bool XBF>
__device__ __forceinline__ void pull_worker(
    const int* __restrict__ off, const int* __restrict__ csr,
    const void* __restrict__ x, bf16* __restrict__ mean, int n, int nsrc,
    int blk0) {
  constexpr int EPL = XBF ? 8 : 4;    // elems per lane (16B either way)
  constexpr int LPR = D / EPL;        // lanes per row
  constexpr int PAR = 64 / LPR;       // edges in parallel
  int node = ((int)blockIdx.x - blk0) * 4 + (threadIdx.x >> 6);
  if (node >= n) return;  // wave-uniform
  int lane = threadIdx.x & 63;
  int h = lane / LPR, col = lane % LPR;
  int beg = off[node], deg = off[node + 1] - beg;
  float inv = 1.0f / fmaxf((float)deg, 1.0f);
  float a[EPL];
#pragma unroll
  for (int e = 0; e < EPL; ++e) a[e] = 0.f;
  for (int i = h; i < deg; i += PAR) {
    int s = csr[beg + i];
    s = ((unsigned)s < (unsigned)nsrc) ? s : 0;
    if (XBF) {
      uint4 v = ((const uint4*)x)[(long long)s * LPR + col];
      a[0] += lo2f(v.x); a[1] += hi2f(v.x);
      a[2] += lo2f(v.y); a[3] += hi2f(v.y);
      a[4] += lo2f(v.z); a[5] += hi2f(v.z);
      a[6] += lo2f(v.w); a[7] += hi2f(v.w);
    } else {
      float4 v = ((const float4*)x)[(long long)s * LPR + col];
      a[0] += v.x; a[1] += v.y; a[2] += v.z; a[3] += v.w;
    }
  }
#pragma unroll
  for (int m = LPR; m < 64; m <<= 1) {
#pragma unroll
    for (int e = 0; e < EPL; ++e) a[e] += __shfl_xor(a[e], m);
  }
  if (h == 0) {
    if (XBF) {
      uint4 o4;
      o4.x = packbf2(a[0] * inv, a[1] * inv);
      o4.y = packbf2(a[2] * inv, a[3] * inv);
      o4.z = packbf2(a[4] * inv, a[5] * inv);
      o4.w = packbf2(a[6] * inv, a[7] * inv);
      ((uint4*)mean)[(long long)node * LPR + col] = o4;
    } else {
      uint2 o2;
      o2.x = packbf2(a[0] * inv, a[1] * inv);
      o2.y = packbf2(a[2] * inv, a[3] * inv);
      ((uint2*)mean)[(long long)node * LPR + col] = o2;
    }
  }
}

// Two independent pull jobs fused into one launch (block-range split):
// removes a dependent-launch gap and lets the small NC job fill CUs
// alongside the NT job instead of running as a half-empty tail.
template <int DA, bool XA, int DB, bool XB>
__global__ __launch_bounds__(256) void pull2_kernel(
    const int* __restrict__ offA, const int* __restrict__ csrA,
    const void* __restrict__ xA, bf16* __restrict__ meanA, int nA, int nsrcA,
    const int* __restrict__ offB, const int* __restrict__ csrB,
    const void* __restrict__ xB, bf16* __restrict__ meanB, int nB, int nsrcB,
    int nblkA) {
  if ((int)blockIdx.x < nblkA)
    pull_worker<DA, XA>(offA, csrA, xA, meanA, nA, nsrcA, 0);
  else
    pull_worker<DB, XB>(offB, csrB, xB, meanB, nB, nsrcB, nblkA);
}

// ======================= MFMA GEMM (no LDS, branch-free, MT row-tiles) =======
// MT = 16-row M-tiles per wave. B fragments loaded once per (kt,t), reused
// across MT MFMAs (R1-validated: fixed the 78us latency wall).
#define AT_BF16 0
#define AT_F32  1
template <int KT, int NCT, int K0T, int A0T, int A1T, bool OUTF32, int MT>
__global__ __launch_bounds__(256, 2) void gemm_kernel(
    const void* __restrict__ A0, int lda0,
    const void* __restrict__ A1, int lda1,
    const ushort* __restrict__ Wt, const float* __restrict__ bias,
    void* __restrict__ C, long long cbase, int ldc, int n, int relu) {
  constexpr int K = KT * 32;
  int tid = threadIdx.x;
  int wave = tid >> 6, lane = tid & 63;
  int p = lane & 15, q = lane >> 4;
  int rowbase = blockIdx.x * (64 * MT) + wave * (16 * MT);

  int rcl[MT];  // A-load row per m-tile (clamped in-bounds)
#pragma unroll
  for (int m = 0; m < MT; ++m) rcl[m] = min(rowbase + m * 16 + p, n - 1);

  float4v acc[MT][NCT];
#pragma unroll
  for (int m = 0; m < MT; ++m)
#pragma unroll
    for (int t = 0; t < NCT; ++t) acc[m][t] = (float4v){0.f, 0.f, 0.f, 0.f};

#pragma unroll
  for (int kt = 0; kt < KT; ++kt) {
    const bool seg0 = (kt < K0T);  // compile-time after unroll
    const void* ab = seg0 ? A0 : A1;
    const int lda = seg0 ? lda0 : lda1;
    const int kof = (seg0 ? kt : (kt - K0T)) * 32;
    const int at = seg0 ? A0T : A1T;
    short8 af[MT];
#pragma unroll
    for (int m = 0; m < MT; ++m) {
      long long base = (long long)rcl[m] * lda + kof + q * 8;
      if (at == AT_BF16) {
        af[m] = *(const short8*)((const bf16*)ab + base);
      } else {
        const float* fb = (const float*)ab + base;
        float4 a = *(const float4*)fb;
        float4 b = *(const float4*)(fb + 4);
        short8 r;
        r[0] = (short)f2bu(a.x); r[1] = (short)f2bu(a.y);
        r[2] = (short)f2bu(a.z); r[3] = (short)f2bu(a.w);
        r[4] = (short)f2bu(b.x); r[5] = (short)f2bu(b.y);
        r[6] = (short)f2bu(b.z); r[7] = (short)f2bu(b.w);
        af[m] = r;
      }
    }
#pragma unroll
    for (int t = 0; t < NCT; ++t) {
      int c = t * 16 + p;
      short8 bfr = *(const short8*)(Wt + (long long)c * K + kt * 32 + q * 8);
#pragma unroll
      for (int m = 0; m < MT; ++m)
        acc[m][t] = __builtin_amdgcn_mfma_f32_16x16x32_bf16(af[m], bfr, acc[m][t], 0, 0, 0);
    }
  }

#pragma unroll
  for (int m = 0; m < MT; ++m) {
#pragma unroll
    for (int t = 0; t < NCT; ++t) {
      int c = t * 16 + p;
      float bv = bias[c];
#pragma unroll
      for (int r = 0; r < 4; ++r) {
        int row = rowbase + m * 16 + q * 4 + r;
        if (row < n) {
          float v = acc[m][t][r] + bv;
          if (relu) v = fmaxf(v, 0.f);
          long long idx = cbase + (long long)row * ldc + c;
          if (OUTF32) ((float*)C)[idx] = v;
          else        ((bf16*)C)[idx] = __float2bfloat16(v);
        }
      }
    }
  }
}

// ======================= fused L2-txn GEMM + decoder =========================
// z = [mean2_ct|h_txn] @ W2ct + b2   (K=256, 128 cols, f32 -> d_out z-slab)
// d1 = relu(z @ Wd1 + bd1)            (LDS round-trip, wave-private tile)
// recon = d1 @ Wd2 + bd2              (f32 -> d_out recon-slab)
// Swapped MFMA operands give z transposed in regs (lane p = row, regs = 4
// consecutive cols) -> ds_write_b64 into XOR-swizzled wave-private LDS,
// read back as A-fragments for decoder stages. R2-validated.
__global__ __launch_bounds__(256, 2) void gemm_fused_dec_kernel(
    const bf16* __restrict__ A0,   // mean2_ct [n][128]
    const bf16* __restrict__ A1,   // h_txn    [n][128]
    const ushort* __restrict__ W3, // Wt3 [128][256]
    const float* __restrict__ b2,  // [128]
    const ushort* __restrict__ W5, // Wt5 [64][128]
    const float* __restrict__ bd1v,// [64]
    const ushort* __restrict__ W6, // Wt6 [64][64]
    const float* __restrict__ bd2v,// [64]
    float* __restrict__ zout,      // d_out + ztxn_base, ld 128
    float* __restrict__ recon,     // d_out, ld 64
    int n) {
  __shared__ __align__(16) char zls[65536];  // 4 waves x 16KB, wave-private
  int tid = threadIdx.x;
  int wave = tid >> 6, lane = tid & 63;
  int p = lane & 15, q = lane >> 4;
  int rowbase = blockIdx.x * 256 + wave * 64;
  char* wls = zls + wave * 16384;
  const int sw = (p & 7) << 4;  // XOR swizzle

  int rcl[4];
#pragma unroll
  for (int m = 0; m < 4; ++m) rcl[m] = min(rowbase + m * 16 + p, n - 1);

  // ---- stage 1: z accumulators (transposed layout) ----
  float4v accz[4][8];
#pragma unroll
  for (int m = 0; m < 4; ++m)
#pragma unroll
    for (int t = 0; t < 8; ++t) accz[m][t] = (float4v){0.f, 0.f, 0.f, 0.f};

#pragma unroll
  for (int kt = 0; kt < 8; ++kt) {
    const bf16* ab = (kt < 4) ? A0 : A1;
    const int kof = (kt & 3) * 32;
    short8 af[4];
#pragma unroll
    for (int m = 0; m < 4; ++m)
      af[m] = *(const short8*)(ab + (long long)rcl[m] * 128 + kof + q * 8);
#pragma unroll
    for (int t = 0; t < 8; ++t) {
      short8 bfr = *(const short8*)(W3 + (long long)(t * 16 + p) * 256 + kt * 32 + q * 8);
#pragma unroll
      for (int m = 0; m < 4; ++m)  // swapped: D[i=col][j=row] => z^T layout
        accz[m][t] = __builtin_amdgcn_mfma_f32_16x16x32_bf16(bfr, af[m], accz[m][t], 0, 0, 0);
    }
  }

  // epilogue: z -> global f32 (+bias), z -> LDS bf16 (row-major [64][256B], swz)
#pragma unroll
  for (int m = 0; m < 4; ++m) {
    int lr = m * 16 + p;           // local row
    int row = rowbase + lr;
#pragma unroll
    for (int t = 0; t < 8; ++t) {
      float4v bz = *(const float4v*)(b2 + t * 16 + q * 4);
      float4v v;
#pragma unroll
      for (int r = 0; r < 4; ++r) v[r] = accz[m][t][r] + bz[r];
      if (row < n)
        *(float4v*)(zout + (long long)row * 128 + t * 16 + q * 4) = v;
      uint2 u;
      u.x = packbf2(v[0], v[1]);
      u.y = packbf2(v[2], v[3]);
      *(uint2*)(wls + (((lr * 256 + t * 32 + q * 8)) ^ sw)) = u;
    }
  }
  __syncthreads();

  // ---- stage 2: d1 = relu(z @ Wd1 + bd1), K=128, 64 cols ----
  float4v accd[4][4];
#pragma unroll
  for (int m = 0; m < 4; ++m)
#pragma unroll
    for (int t = 0; t < 4; ++t) accd[m][t] = (float4v){0.f, 0.f, 0.f, 0.f};

#pragma unroll
  for (int kt2 = 0; kt2 < 4; ++kt2) {
    short8 zf[4];
#pragma unroll
    for (int m = 0; m < 4; ++m)
      zf[m] = *(const short8*)(wls + (((m * 16 + p) * 256 + kt2 * 64 + q * 16) ^ sw));
#pragma unroll
    for (int t2 = 0; t2 < 4; ++t2) {
      short8 wf = *(const short8*)(W5 + (long long)(t2 * 16 + p) * 128 + kt2 * 32 + q * 8);
#pragma unroll
      for (int m = 0; m < 4; ++m)
        accd[m][t2] = __builtin_amdgcn_mfma_f32_16x16x32_bf16(wf, zf[m], accd[m][t2], 0, 0, 0);
    }
  }
  __syncthreads();  // all z-reads done before overwriting region with d1

  // d1 (relu, bf16) -> LDS row-major [64][128B], same swizzle
#pragma unroll
  for (int m = 0; m < 4; ++m) {
    int lr = m * 16 + p;
#pragma unroll
    for (int t2 = 0; t2 < 4; ++t2) {
      float4v bb = *(const float4v*)(bd1v + t2 * 16 + q * 4);
      float4v v;
#pragma unroll
      for (int r = 0; r < 4; ++r) v[r] = fmaxf(accd[m][t2][r] + bb[r], 0.f);
      uint2 u;
      u.x = packbf2(v[0], v[1]);
      u.y = packbf2(v[2], v[3]);
      *(uint2*)(wls + (((lr * 128 + t2 * 32 + q * 8)) ^ sw)) = u;
    }
  }
  // same-wave LDS write->read is in-order; no barrier needed

  // ---- stage 3: recon = d1 @ Wd2 + bd2, K=64, 64 cols ----
  float4v accr[4][4];
#pragma unroll
  for (int m = 0; m < 4; ++m)
#pragma unroll
    for (int t = 0; t < 4; ++t) accr[m][t] = (float4v){0.f, 0.f, 0.f, 0.f};

#pragma unroll
  for (int kt3 = 0; kt3 < 2; ++kt3) {
    short8 df[4];
#pragma unroll
    for (int m = 0; m < 4; ++m)
      df[m] = *(const short8*)(wls + (((m * 16 + p) * 128 + kt3 * 64 + q * 16) ^ sw));
#pragma unroll
    for (int t3 = 0; t3 < 4; ++t3) {
      short8 wf = *(const short8*)(W6 + (long long)(t3 * 16 + p) * 64 + kt3 * 32 + q * 8);
#pragma unroll
      for (int m = 0; m < 4; ++m)
        accr[m][t3] = __builtin_amdgcn_mfma_f32_16x16x32_bf16(wf, df[m], accr[m][t3], 0, 0, 0);
    }
  }

#pragma unroll
  for (int m = 0; m < 4; ++m) {
    int row = rowbase + m * 16 + p;
    if (row < n) {
#pragma unroll
      for (int t3 = 0; t3 < 4; ++t3) {
        float4v bb = *(const float4v*)(bd2v + t3 * 16 + q * 4);
        float4v v;
#pragma unroll
        for (int r = 0; r < 4; ++r) v[r] = accr[m][t3][r] + bb[r];
        *(float4v*)(recon + (long long)row * 64 + t3 * 16 + q * 4) = v;
      }
    }
  }
}

// ======================= host ================================================
extern "C" void kernel_launch(void* const* d_in, const int* in_sizes, int n_in,
                              void* d_out, int out_size, void* d_ws,
                              size_t ws_size, hipStream_t stream) {
  const float* x_txn = (const float*)d_in[0];
  const float* x_cli = (const float*)d_in[1];
  const int* ct_src = (const int*)d_in[2];
  const int* ct_dst = (const int*)d_in[3];
  const int* tc_src = (const int*)d_in[4];
  const int* tc_dst = (const int*)d_in[5];
  const float* W1ctl = (const float*)d_in[6];
  const float* b1ct  = (const float*)d_in[7];
  const float* W1ctr = (const float*)d_in[8];
  const float* W1tcl = (const float*)d_in[9];
  const float* b1tc  = (const float*)d_in[10];
  const float* W1tcr = (const float*)d_in[11];
  const float* W2ctl = (const float*)d_in[12];
  const float* b2ct  = (const float*)d_in[13];
  const float* W2ctr = (const float*)d_in[14];
  const float* W2tcl = (const float*)d_in[15];
  const float* b2tc  = (const float*)d_in[16];
  const float* W2tcr = (const float*)d_in[17];
  const float* Wd1   = (const float*)d_in[18];
  const float* bd1   = (const float*)d_in[19];
  const float* Wd2   = (const float*)d_in[20];
  const float* bd2   = (const float*)d_in[21];

  const int E = in_sizes[2];  // 600000
  const int NT = 100000, NC = 20000;
  const int NBK_CT = (NT + 255) >> 8;  // 391
  const int NBK_TC = (NC + 255) >> 8;  // 79

  // ---- workspace carve ----
  size_t o = 0;
  auto carve = [&](size_t bytes) {
    void* p = (char*)d_ws + o;
    o = (o + bytes + 255) & ~(size_t)255;
    return p;
  };
  int* bcnt_ct = (int*)carve((size_t)NBK_CT * 4);       // zeroed
  int* bcnt_tc = (int*)carve((size_t)NBK_TC * 4);       // zeroed (same page run)
  size_t zero_bytes = o;
  int* boff_ct = (int*)carve((size_t)(NBK_CT + 1) * 4);
  int* boff_tc = (int*)carve((size_t)(NBK_TC + 1) * 4);
  int* bcur_ct = (int*)carve((size_t)NBK_CT * 4);
  int* bcur_tc = (int*)carve((size_t)NBK_TC * 4);
  uint2* se_ct = (uint2*)carve((size_t)E * 8);
  uint2* se_tc = (uint2*)carve((size_t)E * 8);
  int* off_ct = (int*)carve((size_t)(NT + 1) * 4);
  int* off_tc = (int*)carve((size_t)(NC + 1) * 4);
  int* csr_ct = (int*)carve((size_t)E * 4);
  int* csr_tc = (int*)carve((size_t)E * 4);
  ushort* Wt1 = (ushort*)carve((size_t)96 * 128 * 2);
  ushort* Wt2 = (ushort*)carve((size_t)96 * 128 * 2);
  ushort* Wt3 = (ushort*)carve((size_t)256 * 128 * 2);
  ushort* Wt4 = (ushort*)carve((size_t)256 * 128 * 2);
  ushort* Wt5 = (ushort*)carve((size_t)128 * 64 * 2);
  ushort* Wt6 = (ushort*)carve((size_t)64 * 64 * 2);
  bf16* mean1_ct = (bf16*)carve((size_t)NT * 32 * 2);
  bf16* mean1_tc = (bf16*)carve((size_t)NC * 64 * 2);
  bf16* h_txn    = (bf16*)carve((size_t)NT * 128 * 2);
  bf16* h_cli    = (bf16*)carve((size_t)NC * 128 * 2);
  bf16* mean2_ct = (bf16*)carve((size_t)NT * 128 * 2);
  bf16* mean2_tc = (bf16*)carve((size_t)NC * 128 * 2);
  (void)ws_size;

  hipMemsetAsync(d_ws, 0, zero_bytes, stream);

  const int tb = 256;
  const int CH = (E + 4095) / 4096;  // 147 chunks per edge type

  // ---- fused weight transposes (1 launch) ----
  {
    TJobs js;
    auto blocks = [](int k, int ncol) { return (k * ncol + 255) / 256; };
    int boff = 0;
    auto setj = [&](int idx, const float* wl, const float* wr, ushort* dst,
                    int da, int k, int ncol) {
      js.j[idx] = TJob{wl, wr, dst, da, k, ncol, boff};
      boff += blocks(k, ncol);
    };
    setj(0, W1ctl, W1ctr, Wt1, 32, 96, 128);
    setj(1, W1tcl, W1tcr, Wt2, 64, 96, 128);
    setj(2, W2ctl, W2ctr, Wt3, 128, 256, 128);
    setj(3, W2tcl, W2tcr, Wt4, 128, 256, 128);
    setj(4, Wd1, Wd1, Wt5, 128, 128, 64);
    setj(5, Wd2, Wd2, Wt6, 64, 64, 64);
    transpose6_kernel<<<boff, tb, 0, stream>>>(js);
  }

  // ---- CSR build: two-level counting sort (both edge types fused) ----
  bhist_kernel<<<2 * CH, tb, 0, stream>>>(ct_dst, bcnt_ct, NBK_CT,
                                          tc_dst, bcnt_tc, NBK_TC, E, CH);
  bscan_kernel<<<2, 512, 0, stream>>>(bcnt_ct, boff_ct, bcur_ct, NBK_CT,
                                      bcnt_tc, boff_tc, bcur_tc, NBK_TC);
  multisplit_kernel<<<2 * CH, tb, 0, stream>>>(
      ct_src, ct_dst, bcur_ct, se_ct, NBK_CT,
      tc_src, tc_dst, bcur_tc, se_tc, NBK_TC, E, CH);
  csr_fine_kernel<<<NBK_CT + NBK_TC, tb, 0, stream>>>(
      se_ct, boff_ct, off_ct, csr_ct, NT, NBK_CT,
      se_tc, boff_tc, off_tc, csr_tc, NC);

  auto gbm = [](int n, int mt) { return (n + 64 * mt - 1) / (64 * mt); };
  const int pbA = (NT + 3) / 4, pbB = (NC + 3) / 4;

  // ---- layer 1: fused pull means (fp32 inputs) then fused linears ----
  pull2_kernel<32, false, 64, false><<<pbA + pbB, tb, 0, stream>>>(
      off_ct, csr_ct, x_cli, mean1_ct, NT, NC,
      off_tc, csr_tc, x_txn, mean1_tc, NC, NT, pbA);

  gemm_kernel<3, 8, 1, AT_BF16, AT_F32, false, 4><<<gbm(NT, 4), tb, 0, stream>>>(
      mean1_ct, 32, x_txn, 64, Wt1, b1ct, h_txn, 0, 128, NT, 1);
  gemm_kernel<3, 8, 2, AT_BF16, AT_F32, false, 1><<<gbm(NC, 1), tb, 0, stream>>>(
      mean1_tc, 64, x_cli, 32, Wt2, b1tc, h_cli, 0, 128, NC, 1);

  // ---- layer 2: fused pull means (bf16 h) ----
  pull2_kernel<128, true, 128, true><<<pbA + pbB, tb, 0, stream>>>(
      off_ct, csr_ct, h_cli, mean2_ct, NT, NC,
      off_tc, csr_tc, h_txn, mean2_tc, NC, NT, pbA);

  float* out = (float*)d_out;
  const long long ztxn_base = (long long)NT * 64;
  const long long zcli_base = ztxn_base + (long long)NT * 128;

  // ---- fused: z_txn + decoder (replaces 3 kernels) ----
  gemm_fused_dec_kernel<<<gbm(NT, 4), tb, 0, stream>>>(
      mean2_ct, h_txn, Wt3, b2ct, Wt5, bd1, Wt6, bd2,
      out + ztxn_base, out, NT);

  gemm_kernel<8, 8, 4, AT_BF16, AT_BF16, true, 1><<<gbm(NC, 1), tb, 0, stream>>>(
      mean2_tc, 128, h_cli, 128, Wt4, b2tc, out, zcli_base, 128, NC, 0);
}

// Round 4
// 376.646 us; speedup vs baseline: 1.2750x; 1.0198x over previous
//
#include <hip/hip_runtime.h>
#include <hip/hip_bf16.h>

typedef __hip_bfloat16 bf16;
typedef unsigned int uint;
typedef unsigned short ushort;
typedef __attribute__((ext_vector_type(8))) short short8;   // 8 bf16 = 4 VGPR
typedef __attribute__((ext_vector_type(4))) float float4v;  // MFMA acc

__device__ __forceinline__ float lo2f(uint v) { return __uint_as_float(v << 16); }
__device__ __forceinline__ float hi2f(uint v) { return __uint_as_float(v & 0xffff0000u); }
__device__ __forceinline__ ushort f2bu(float v) {
  union { bf16 h; ushort u; } x;
  x.h = __float2bfloat16(v);
  return x.u;
}
__device__ __forceinline__ uint packbf2(float a, float b) {
  return (uint)f2bu(a) | ((uint)f2bu(b) << 16);
}

#define BSH 8          // bucket shift: 256 nodes per bucket
#define NBK_MAX 391    // max buckets (txn side)

// ======================= fused weight transpose (6 jobs, 1 launch) ===========
struct TJob { const float* wl; const float* wr; ushort* dst; int da, k, ncol, boff; };
struct TJobs { TJob j[6]; };

__global__ void transpose6_kernel(TJobs js) {
  int b = blockIdx.x;
  int jj = 0;
#pragma unroll
  for (int t = 1; t < 6; ++t)
    if (b >= js.j[t].boff) jj = t;
  const TJob J = js.j[jj];
  int i = (b - J.boff) * 256 + threadIdx.x;
  if (i >= J.k * J.ncol) return;
  int k = i / J.ncol, c = i - k * J.ncol;
  const float* srcp = (k < J.da) ? (J.wl + (long long)k * J.ncol)
                                 : (J.wr + (long long)(k - J.da) * J.ncol);
  J.dst[(long long)c * J.k + k] = f2bu(srcp[c]);
}

// ======================= CSR build, two-level counting sort ==================
// Phase 1: coarse histogram of dst>>BSH (LDS per block, atomic merge).
__global__ void bhist_kernel(const int* __restrict__ dA, int* __restrict__ cA, int nbkA,
                             const int* __restrict__ dB, int* __restrict__ cB, int nbkB,
                             int E, int chA) {
  __shared__ int h[NBK_MAX];
  int b = blockIdx.x;
  const int* dst; int* gc; int nbk;
  if (b < chA) { dst = dA; gc = cA; nbk = nbkA; }
  else         { b -= chA; dst = dB; gc = cB; nbk = nbkB; }
  for (int i = threadIdx.x; i < nbk; i += 256) h[i] = 0;
  __syncthreads();
  int e0 = b * 4096;
  for (int j = 0; j < 16; ++j) {
    int e = e0 + j * 256 + threadIdx.x;
    if (e < E) {
      uint B = (uint)dst[e] >> BSH;
      if (B < (uint)nbk) atomicAdd(&h[B], 1);
    }
  }
  __syncthreads();
  for (int i = threadIdx.x; i < nbk; i += 256)
    if (h[i]) atomicAdd(&gc[i], h[i]);
}

// Phase 2: exclusive scan of bucket counts -> bucket offsets + cursors.
__global__ void bscan_kernel(const int* __restrict__ cA, int* __restrict__ oA,
                             int* __restrict__ uA, int nbkA,
                             const int* __restrict__ cB, int* __restrict__ oB,
                             int* __restrict__ uB, int nbkB) {
  __shared__ int s[512];
  const int* cnt; int* off; int* cur; int nbk;
  if (blockIdx.x == 0) { cnt = cA; off = oA; cur = uA; nbk = nbkA; }
  else                 { cnt = cB; off = oB; cur = uB; nbk = nbkB; }
  int t = threadIdx.x;
  int v = (t < nbk) ? cnt[t] : 0;
  s[t] = v;
  __syncthreads();
  for (int o = 1; o < 512; o <<= 1) {
    int x = (t >= o) ? s[t - o] : 0;
    __syncthreads();
    s[t] += x;
    __syncthreads();
  }
  if (t < nbk) { int ex = s[t] - v; off[t] = ex; cur[t] = ex; }
  if (t == nbk - 1) off[nbk] = s[t];
}

// Phase 3: multisplit — scatter (src,dst) into bucket-sorted uint2 array.
// Per-block LDS ranking => per (block,bucket) contiguous write runs.
__global__ void multisplit_kernel(const int* __restrict__ sA, const int* __restrict__ dA,
                                  int* __restrict__ uA, uint2* __restrict__ seA, int nbkA,
                                  const int* __restrict__ sB, const int* __restrict__ dB,
                                  int* __restrict__ uB, uint2* __restrict__ seB, int nbkB,
                                  int E, int chA) {
  __shared__ int cnt[NBK_MAX];
  __shared__ int base[NBK_MAX];
  int b = blockIdx.x;
  const int *src, *dst; int* gcur; uint2* se; int nbk;
  if (b < chA) { src = sA; dst = dA; gcur = uA; se = seA; nbk = nbkA; }
  else         { b -= chA; src = sB; dst = dB; gcur = uB; se = seB; nbk = nbkB; }
  for (int i = threadIdx.x; i < nbk; i += 256) cnt[i] = 0;
  __syncthreads();
  int e0 = b * 4096;
  int mys[16], myd[16], myb[16], myr[16];
#pragma unroll
  for (int j = 0; j < 16; ++j) {
    int e = e0 + j * 256 + threadIdx.x;
    int s = 0, d = 0, bb = -1, r = 0;
    if (e < E) {
      s = src[e]; d = dst[e];
      uint B = (uint)d >> BSH;
      if (B < (uint)nbk) { bb = (int)B; r = atomicAdd(&cnt[bb], 1); }
    }
    mys[j] = s; myd[j] = d; myb[j] = bb; myr[j] = r;
  }
  __syncthreads();
  for (int i = threadIdx.x; i < nbk; i += 256) {
    int c = cnt[i];
    base[i] = c ? atomicAdd(&gcur[i], c) : 0;
  }
  __syncthreads();
#pragma unroll
  for (int j = 0; j < 16; ++j) {
    if (myb[j] >= 0) {
      uint2 v; v.x = (uint)mys[j]; v.y = (uint)myd[j];
      se[base[myb[j]] + myr[j]] = v;
    }
  }
}

// Phase 4: per-bucket fine CSR — one block per bucket, all ranking in LDS.
__global__ void csr_fine_kernel(const uint2* __restrict__ seA, const int* __restrict__ boA,
                                int* __restrict__ offA, int* __restrict__ csrA, int nA, int nbkA,
                                const uint2* __restrict__ seB, const int* __restrict__ boB,
                                int* __restrict__ offB, int* __restrict__ csrB, int nB) {
  __shared__ int s[256];
  __shared__ int cur[256];
  int b = blockIdx.x;
  const uint2* se; const int* bo; int* off; int* csr; int n;
  if (b < nbkA) { se = seA; bo = boA; off = offA; csr = csrA; n = nA; }
  else          { b -= nbkA; se = seB; bo = boB; off = offB; csr = csrB; n = nB; }
  int t = threadIdx.x;
  int ebeg = bo[b], eend = bo[b + 1];
  // local degree histogram
  cur[t] = 0;
  __syncthreads();
  for (int i = ebeg + t; i < eend; i += 256)
    atomicAdd(&cur[se[i].y & 255], 1);
  __syncthreads();
  int v = cur[t];
  s[t] = v;
  __syncthreads();
  for (int o = 1; o < 256; o <<= 1) {
    int x = (t >= o) ? s[t - o] : 0;
    __syncthreads();
    s[t] += x;
    __syncthreads();
  }
  int excl = s[t] - v;
  int node = b * 256 + t;
  if (node < n) off[node] = ebeg + excl;
  if (node == n - 1) off[n] = ebeg + excl + v;
  cur[t] = excl;
  __syncthreads();
  for (int i = ebeg + t; i < eend; i += 256) {
    uint2 e = se[i];
    int pos = ebeg + atomicAdd(&cur[e.y & 255], 1);
    csr[pos] = (int)e.x;
  }
}

// ======================= pull aggregation (mean, bf16 out) ===================
// 16B/lane gathers; 4-deep unrolled gather pipeline (R3): issue 4 independent
// csr-index loads, then 4 independent row loads -> MLP 1->4 on the dependent
// idx->row chain that dominated the 59us layer-2 pull. Accumulation order per
// (lane,slot) identical to the rolled loop => bit-identical results.
__device__ __forceinline__ void acc8(float* a, uint4 v) {
  a[0] += lo2f(v.x); a[1] += hi2f(v.x);
  a[2] += lo2f(v.y); a[3] += hi2f(v.y);
  a[4] += lo2f(v.z); a[5] += hi2f(v.z);
  a[6] += lo2f(v.w); a[7] += hi2f(v.w);
}
__device__ __forceinline__ void acc4(float* a, float4 v) {
  a[0] += v.x; a[1] += v.y; a[2] += v.z; a[3] += v.w;
}

template <int D, bool XBF>
__device__ __forceinline__ void pull_worker(
    const int* __restrict__ off, const int* __restrict__ csr,
    const void* __restrict__ x, bf16* __restrict__ mean, int n, int nsrc,
    int blk0) {
  constexpr int EPL = XBF ? 8 : 4;    // elems per lane (16B either way)
  constexpr int LPR = D / EPL;        // lanes per row
  constexpr int PAR = 64 / LPR;       // edges in parallel
  int node = ((int)blockIdx.x - blk0) * 4 + (threadIdx.x >> 6);
  if (node >= n) return;  // wave-uniform
  int lane = threadIdx.x & 63;
  int h = lane / LPR, col = lane % LPR;
  int beg = off[node], deg = off[node + 1] - beg;
  float inv = 1.0f / fmaxf((float)deg, 1.0f);
  float a[EPL];
#pragma unroll
  for (int e = 0; e < EPL; ++e) a[e] = 0.f;

  int i = h;
  // main loop: 4 edge-rounds in flight
  for (; i + 3 * PAR < deg; i += 4 * PAR) {
    int s0 = csr[beg + i];
    int s1 = csr[beg + i + PAR];
    int s2 = csr[beg + i + 2 * PAR];
    int s3 = csr[beg + i + 3 * PAR];
    s0 = ((unsigned)s0 < (unsigned)nsrc) ? s0 : 0;
    s1 = ((unsigned)s1 < (unsigned)nsrc) ? s1 : 0;
    s2 = ((unsigned)s2 < (unsigned)nsrc) ? s2 : 0;
    s3 = ((unsigned)s3 < (unsigned)nsrc) ? s3 : 0;
    if (XBF) {
      uint4 v0 = ((const uint4*)x)[(long long)s0 * LPR + col];
      uint4 v1 = ((const uint4*)x)[(long long)s1 * LPR + col];
      uint4 v2 = ((const uint4*)x)[(long long)s2 * LPR + col];
      uint4 v3 = ((const uint4*)x)[(long long)s3 * LPR + col];
      acc8(a, v0); acc8(a, v1); acc8(a, v2); acc8(a, v3);
    } else {
      float4 v0 = ((const float4*)x)[(long long)s0 * LPR + col];
      float4 v1 = ((const float4*)x)[(long long)s1 * LPR + col];
      float4 v2 = ((const float4*)x)[(long long)s2 * LPR + col];
      float4 v3 = ((const float4*)x)[(long long)s3 * LPR + col];
      acc4(a, v0); acc4(a, v1); acc4(a, v2); acc4(a, v3);
    }
  }
  // tail
  for (; i < deg; i += PAR) {
    int s = csr[beg + i];
    s = ((unsigned)s < (unsigned)nsrc) ? s : 0;
    if (XBF) {
      uint4 v = ((const uint4*)x)[(long long)s * LPR + col];
      acc8(a, v);
    } else {
      float4 v = ((const float4*)x)[(long long)s * LPR + col];
      acc4(a, v);
    }
  }

#pragma unroll
  for (int m = LPR; m < 64; m <<= 1) {
#pragma unroll
    for (int e = 0; e < EPL; ++e) a[e] += __shfl_xor(a[e], m);
  }
  if (h == 0) {
    if (XBF) {
      uint4 o4;
      o4.x = packbf2(a[0] * inv, a[1] * inv);
      o4.y = packbf2(a[2] * inv, a[3] * inv);
      o4.z = packbf2(a[4] * inv, a[5] * inv);
      o4.w = packbf2(a[6] * inv, a[7] * inv);
      ((uint4*)mean)[(long long)node * LPR + col] = o4;
    } else {
      uint2 o2;
      o2.x = packbf2(a[0] * inv, a[1] * inv);
      o2.y = packbf2(a[2] * inv, a[3] * inv);
      ((uint2*)mean)[(long long)node * LPR + col] = o2;
    }
  }
}

// Two independent pull jobs fused into one launch (block-range split).
template <int DA, bool XA, int DB, bool XB>
__global__ __launch_bounds__(256) void pull2_kernel(
    const int* __restrict__ offA, const int* __restrict__ csrA,
    const void* __restrict__ xA, bf16* __restrict__ meanA, int nA, int nsrcA,
    const int* __restrict__ offB, const int* __restrict__ csrB,
    const void* __restrict__ xB, bf16* __restrict__ meanB, int nB, int nsrcB,
    int nblkA) {
  if ((int)blockIdx.x < nblkA)
    pull_worker<DA, XA>(offA, csrA, xA, meanA, nA, nsrcA, 0);
  else
    pull_worker<DB, XB>(offB, csrB, xB, meanB, nB, nsrcB, nblkA);
}

// ======================= MFMA GEMM (no LDS, branch-free, MT row-tiles) =======
// MT = 16-row M-tiles per wave. B fragments loaded once per (kt,t), reused
// across MT MFMAs (R1-validated: fixed the 78us latency wall).
#define AT_BF16 0
#define AT_F32  1
template <int KT, int NCT, int K0T, int A0T, int A1T, bool OUTF32, int MT>
__global__ __launch_bounds__(256, 2) void gemm_kernel(
    const void* __restrict__ A0, int lda0,
    const void* __restrict__ A1, int lda1,
    const ushort* __restrict__ Wt, const float* __restrict__ bias,
    void* __restrict__ C, long long cbase, int ldc, int n, int relu) {
  constexpr int K = KT * 32;
  int tid = threadIdx.x;
  int wave = tid >> 6, lane = tid & 63;
  int p = lane & 15, q = lane >> 4;
  int rowbase = blockIdx.x * (64 * MT) + wave * (16 * MT);

  int rcl[MT];  // A-load row per m-tile (clamped in-bounds)
#pragma unroll
  for (int m = 0; m < MT; ++m) rcl[m] = min(rowbase + m * 16 + p, n - 1);

  float4v acc[MT][NCT];
#pragma unroll
  for (int m = 0; m < MT; ++m)
#pragma unroll
    for (int t = 0; t < NCT; ++t) acc[m][t] = (float4v){0.f, 0.f, 0.f, 0.f};

#pragma unroll
  for (int kt = 0; kt < KT; ++kt) {
    const bool seg0 = (kt < K0T);  // compile-time after unroll
    const void* ab = seg0 ? A0 : A1;
    const int lda = seg0 ? lda0 : lda1;
    const int kof = (seg0 ? kt : (kt - K0T)) * 32;
    const int at = seg0 ? A0T : A1T;
    short8 af[MT];
#pragma unroll
    for (int m = 0; m < MT; ++m) {
      long long base = (long long)rcl[m] * lda + kof + q * 8;
      if (at == AT_BF16) {
        af[m] = *(const short8*)((const bf16*)ab + base);
      } else {
        const float* fb = (const float*)ab + base;
        float4 a = *(const float4*)fb;
        float4 b = *(const float4*)(fb + 4);
        short8 r;
        r[0] = (short)f2bu(a.x); r[1] = (short)f2bu(a.y);
        r[2] = (short)f2bu(a.z); r[3] = (short)f2bu(a.w);
        r[4] = (short)f2bu(b.x); r[5] = (short)f2bu(b.y);
        r[6] = (short)f2bu(b.z); r[7] = (short)f2bu(b.w);
        af[m] = r;
      }
    }
#pragma unroll
    for (int t = 0; t < NCT; ++t) {
      int c = t * 16 + p;
      short8 bfr = *(const short8*)(Wt + (long long)c * K + kt * 32 + q * 8);
#pragma unroll
      for (int m = 0; m < MT; ++m)
        acc[m][t] = __builtin_amdgcn_mfma_f32_16x16x32_bf16(af[m], bfr, acc[m][t], 0, 0, 0);
    }
  }

#pragma unroll
  for (int m = 0; m < MT; ++m) {
#pragma unroll
    for (int t = 0; t < NCT; ++t) {
      int c = t * 16 + p;
      float bv = bias[c];
#pragma unroll
      for (int r = 0; r < 4; ++r) {
        int row = rowbase + m * 16 + q * 4 + r;
        if (row < n) {
          float v = acc[m][t][r] + bv;
          if (relu) v = fmaxf(v, 0.f);
          long long idx = cbase + (long long)row * ldc + c;
          if (OUTF32) ((float*)C)[idx] = v;
          else        ((bf16*)C)[idx] = __float2bfloat16(v);
        }
      }
    }
  }
}

// ======================= fused L2-txn GEMM + decoder =========================
// z = [mean2_ct|h_txn] @ W2ct + b2   (K=256, 128 cols, f32 -> d_out z-slab)
// d1 = relu(z @ Wd1 + bd1)            (LDS round-trip, wave-private tile)
// recon = d1 @ Wd2 + bd2              (f32 -> d_out recon-slab)
// Swapped MFMA operands give z transposed in regs (lane p = row, regs = 4
// consecutive cols) -> ds_write_b64 into XOR-swizzled wave-private LDS,
// read back as A-fragments for decoder stages. R2-validated.
__global__ __launch_bounds__(256, 2) void gemm_fused_dec_kernel(
    const bf16* __restrict__ A0,   // mean2_ct [n][128]
    const bf16* __restrict__ A1,   // h_txn    [n][128]
    const ushort* __restrict__ W3, // Wt3 [128][256]
    const float* __restrict__ b2,  // [128]
    const ushort* __restrict__ W5, // Wt5 [64][128]
    const float* __restrict__ bd1v,// [64]
    const ushort* __restrict__ W6, // Wt6 [64][64]
    const float* __restrict__ bd2v,// [64]
    float* __restrict__ zout,      // d_out + ztxn_base, ld 128
    float* __restrict__ recon,     // d_out, ld 64
    int n) {
  __shared__ __align__(16) char zls[65536];  // 4 waves x 16KB, wave-private
  int tid = threadIdx.x;
  int wave = tid >> 6, lane = tid & 63;
  int p = lane & 15, q = lane >> 4;
  int rowbase = blockIdx.x * 256 + wave * 64;
  char* wls = zls + wave * 16384;
  const int sw = (p & 7) << 4;  // XOR swizzle

  int rcl[4];
#pragma unroll
  for (int m = 0; m < 4; ++m) rcl[m] = min(rowbase + m * 16 + p, n - 1);

  // ---- stage 1: z accumulators (transposed layout) ----
  float4v accz[4][8];
#pragma unroll
  for (int m = 0; m < 4; ++m)
#pragma unroll
    for (int t = 0; t < 8; ++t) accz[m][t] = (float4v){0.f, 0.f, 0.f, 0.f};

#pragma unroll
  for (int kt = 0; kt < 8; ++kt) {
    const bf16* ab = (kt < 4) ? A0 : A1;
    const int kof = (kt & 3) * 32;
    short8 af[4];
#pragma unroll
    for (int m = 0; m < 4; ++m)
      af[m] = *(const short8*)(ab + (long long)rcl[m] * 128 + kof + q * 8);
#pragma unroll
    for (int t = 0; t < 8; ++t) {
      short8 bfr = *(const short8*)(W3 + (long long)(t * 16 + p) * 256 + kt * 32 + q * 8);
#pragma unroll
      for (int m = 0; m < 4; ++m)  // swapped: D[i=col][j=row] => z^T layout
        accz[m][t] = __builtin_amdgcn_mfma_f32_16x16x32_bf16(bfr, af[m], accz[m][t], 0, 0, 0);
    }
  }

  // epilogue: z -> global f32 (+bias), z -> LDS bf16 (row-major [64][256B], swz)
#pragma unroll
  for (int m = 0; m < 4; ++m) {
    int lr = m * 16 + p;           // local row
    int row = rowbase + lr;
#pragma unroll
    for (int t = 0; t < 8; ++t) {
      float4v bz = *(const float4v*)(b2 + t * 16 + q * 4);
      float4v v;
#pragma unroll
      for (int r = 0; r < 4; ++r) v[r] = accz[m][t][r] + bz[r];
      if (row < n)
        *(float4v*)(zout + (long long)row * 128 + t * 16 + q * 4) = v;
      uint2 u;
      u.x = packbf2(v[0], v[1]);
      u.y = packbf2(v[2], v[3]);
      *(uint2*)(wls + (((lr * 256 + t * 32 + q * 8)) ^ sw)) = u;
    }
  }
  __syncthreads();

  // ---- stage 2: d1 = relu(z @ Wd1 + bd1), K=128, 64 cols ----
  float4v accd[4][4];
#pragma unroll
  for (int m = 0; m < 4; ++m)
#pragma unroll
    for (int t = 0; t < 4; ++t) accd[m][t] = (float4v){0.f, 0.f, 0.f, 0.f};

#pragma unroll
  for (int kt2 = 0; kt2 < 4; ++kt2) {
    short8 zf[4];
#pragma unroll
    for (int m = 0; m < 4; ++m)
      zf[m] = *(const short8*)(wls + (((m * 16 + p) * 256 + kt2 * 64 + q * 16) ^ sw));
#pragma unroll
    for (int t2 = 0; t2 < 4; ++t2) {
      short8 wf = *(const short8*)(W5 + (long long)(t2 * 16 + p) * 128 + kt2 * 32 + q * 8);
#pragma unroll
      for (int m = 0; m < 4; ++m)
        accd[m][t2] = __builtin_amdgcn_mfma_f32_16x16x32_bf16(wf, zf[m], accd[m][t2], 0, 0, 0);
    }
  }
  __syncthreads();  // all z-reads done before overwriting region with d1

  // d1 (relu, bf16) -> LDS row-major [64][128B], same swizzle
#pragma unroll
  for (int m = 0; m < 4; ++m) {
    int lr = m * 16 + p;
#pragma unroll
    for (int t2 = 0; t2 < 4; ++t2) {
      float4v bb = *(const float4v*)(bd1v + t2 * 16 + q * 4);
      float4v v;
#pragma unroll
      for (int r = 0; r < 4; ++r) v[r] = fmaxf(accd[m][t2][r] + bb[r], 0.f);
      uint2 u;
      u.x = packbf2(v[0], v[1]);
      u.y = packbf2(v[2], v[3]);
      *(uint2*)(wls + (((lr * 128 + t2 * 32 + q * 8)) ^ sw)) = u;
    }
  }
  // same-wave LDS write->read is in-order; no barrier needed

  // ---- stage 3: recon = d1 @ Wd2 + bd2, K=64, 64 cols ----
  float4v accr[4][4];
#pragma unroll
  for (int m = 0; m < 4; ++m)
#pragma unroll
    for (int t = 0; t < 4; ++t) accr[m][t] = (float4v){0.f, 0.f, 0.f, 0.f};

#pragma unroll
  for (int kt3 = 0; kt3 < 2; ++kt3) {
    short8 df[4];
#pragma unroll
    for (int m = 0; m < 4; ++m)
      df[m] = *(const short8*)(wls + (((m * 16 + p) * 128 + kt3 * 64 + q * 16) ^ sw));
#pragma unroll
    for (int t3 = 0; t3 < 4; ++t3) {
      short8 wf = *(const short8*)(W6 + (long long)(t3 * 16 + p) * 64 + kt3 * 32 + q * 8);
#pragma unroll
      for (int m = 0; m < 4; ++m)
        accr[m][t3] = __builtin_amdgcn_mfma_f32_16x16x32_bf16(wf, df[m], accr[m][t3], 0, 0, 0);
    }
  }

#pragma unroll
  for (int m = 0; m < 4; ++m) {
    int row = rowbase + m * 16 + p;
    if (row < n) {
#pragma unroll
      for (int t3 = 0; t3 < 4; ++t3) {
        float4v bb = *(const float4v*)(bd2v + t3 * 16 + q * 4);
        float4v v;
#pragma unroll
        for (int r = 0; r < 4; ++r) v[r] = accr[m][t3][r] + bb[r];
        *(float4v*)(recon + (long long)row * 64 + t3 * 16 + q * 4) = v;
      }
    }
  }
}

// ======================= host ================================================
extern "C" void kernel_launch(void* const* d_in, const int* in_sizes, int n_in,
                              void* d_out, int out_size, void* d_ws,
                              size_t ws_size, hipStream_t stream) {
  const float* x_txn = (const float*)d_in[0];
  const float* x_cli = (const float*)d_in[1];
  const int* ct_src = (const int*)d_in[2];
  const int* ct_dst = (const int*)d_in[3];
  const int* tc_src = (const int*)d_in[4];
  const int* tc_dst = (const int*)d_in[5];
  const float* W1ctl = (const float*)d_in[6];
  const float* b1ct  = (const float*)d_in[7];
  const float* W1ctr = (const float*)d_in[8];
  const float* W1tcl = (const float*)d_in[9];
  const float* b1tc  = (const float*)d_in[10];
  const float* W1tcr = (const float*)d_in[11];
  const float* W2ctl = (const float*)d_in[12];
  const float* b2ct  = (const float*)d_in[13];
  const float* W2ctr = (const float*)d_in[14];
  const float* W2tcl = (const float*)d_in[15];
  const float* b2tc  = (const float*)d_in[16];
  const float* W2tcr = (const float*)d_in[17];
  const float* Wd1   = (const float*)d_in[18];
  const float* bd1   = (const float*)d_in[19];
  const float* Wd2   = (const float*)d_in[20];
  const float* bd2   = (const float*)d_in[21];

  const int E = in_sizes[2];  // 600000
  const int NT = 100000, NC = 20000;
  const int NBK_CT = (NT + 255) >> 8;  // 391
  const int NBK_TC = (NC + 255) >> 8;  // 79

  // ---- workspace carve ----
  size_t o = 0;
  auto carve = [&](size_t bytes) {
    void* p = (char*)d_ws + o;
    o = (o + bytes + 255) & ~(size_t)255;
    return p;
  };
  int* bcnt_ct = (int*)carve((size_t)NBK_CT * 4);       // zeroed
  int* bcnt_tc = (int*)carve((size_t)NBK_TC * 4);       // zeroed (same page run)
  size_t zero_bytes = o;
  int* boff_ct = (int*)carve((size_t)(NBK_CT + 1) * 4);
  int* boff_tc = (int*)carve((size_t)(NBK_TC + 1) * 4);
  int* bcur_ct = (int*)carve((size_t)NBK_CT * 4);
  int* bcur_tc = (int*)carve((size_t)NBK_TC * 4);
  uint2* se_ct = (uint2*)carve((size_t)E * 8);
  uint2* se_tc = (uint2*)carve((size_t)E * 8);
  int* off_ct = (int*)carve((size_t)(NT + 1) * 4);
  int* off_tc = (int*)carve((size_t)(NC + 1) * 4);
  int* csr_ct = (int*)carve((size_t)E * 4);
  int* csr_tc = (int*)carve((size_t)E * 4);
  ushort* Wt1 = (ushort*)carve((size_t)96 * 128 * 2);
  ushort* Wt2 = (ushort*)carve((size_t)96 * 128 * 2);
  ushort* Wt3 = (ushort*)carve((size_t)256 * 128 * 2);
  ushort* Wt4 = (ushort*)carve((size_t)256 * 128 * 2);
  ushort* Wt5 = (ushort*)carve((size_t)128 * 64 * 2);
  ushort* Wt6 = (ushort*)carve((size_t)64 * 64 * 2);
  bf16* mean1_ct = (bf16*)carve((size_t)NT * 32 * 2);
  bf16* mean1_tc = (bf16*)carve((size_t)NC * 64 * 2);
  bf16* h_txn    = (bf16*)carve((size_t)NT * 128 * 2);
  bf16* h_cli    = (bf16*)carve((size_t)NC * 128 * 2);
  bf16* mean2_ct = (bf16*)carve((size_t)NT * 128 * 2);
  bf16* mean2_tc = (bf16*)carve((size_t)NC * 128 * 2);
  (void)ws_size;

  hipMemsetAsync(d_ws, 0, zero_bytes, stream);

  const int tb = 256;
  const int CH = (E + 4095) / 4096;  // 147 chunks per edge type

  // ---- fused weight transposes (1 launch) ----
  {
    TJobs js;
    auto blocks = [](int k, int ncol) { return (k * ncol + 255) / 256; };
    int boff = 0;
    auto setj = [&](int idx, const float* wl, const float* wr, ushort* dst,
                    int da, int k, int ncol) {
      js.j[idx] = TJob{wl, wr, dst, da, k, ncol, boff};
      boff += blocks(k, ncol);
    };
    setj(0, W1ctl, W1ctr, Wt1, 32, 96, 128);
    setj(1, W1tcl, W1tcr, Wt2, 64, 96, 128);
    setj(2, W2ctl, W2ctr, Wt3, 128, 256, 128);
    setj(3, W2tcl, W2tcr, Wt4, 128, 256, 128);
    setj(4, Wd1, Wd1, Wt5, 128, 128, 64);
    setj(5, Wd2, Wd2, Wt6, 64, 64, 64);
    transpose6_kernel<<<boff, tb, 0, stream>>>(js);
  }

  // ---- CSR build: two-level counting sort (both edge types fused) ----
  bhist_kernel<<<2 * CH, tb, 0, stream>>>(ct_dst, bcnt_ct, NBK_CT,
                                          tc_dst, bcnt_tc, NBK_TC, E, CH);
  bscan_kernel<<<2, 512, 0, stream>>>(bcnt_ct, boff_ct, bcur_ct, NBK_CT,
                                      bcnt_tc, boff_tc, bcur_tc, NBK_TC);
  multisplit_kernel<<<2 * CH, tb, 0, stream>>>(
      ct_src, ct_dst, bcur_ct, se_ct, NBK_CT,
      tc_src, tc_dst, bcur_tc, se_tc, NBK_TC, E, CH);
  csr_fine_kernel<<<NBK_CT + NBK_TC, tb, 0, stream>>>(
      se_ct, boff_ct, off_ct, csr_ct, NT, NBK_CT,
      se_tc, boff_tc, off_tc, csr_tc, NC);

  auto gbm = [](int n, int mt) { return (n + 64 * mt - 1) / (64 * mt); };
  const int pbA = (NT + 3) / 4, pbB = (NC + 3) / 4;

  // ---- layer 1: fused pull means (fp32 inputs) then fused linears ----
  pull2_kernel<32, false, 64, false><<<pbA + pbB, tb, 0, stream>>>(
      off_ct, csr_ct, x_cli, mean1_ct, NT, NC,
      off_tc, csr_tc, x_txn, mean1_tc, NC, NT, pbA);

  gemm_kernel<3, 8, 1, AT_BF16, AT_F32, false, 4><<<gbm(NT, 4), tb, 0, stream>>>(
      mean1_ct, 32, x_txn, 64, Wt1, b1ct, h_txn, 0, 128, NT, 1);
  gemm_kernel<3, 8, 2, AT_BF16, AT_F32, false, 1><<<gbm(NC, 1), tb, 0, stream>>>(
      mean1_tc, 64, x_cli, 32, Wt2, b1tc, h_cli, 0, 128, NC, 1);

  // ---- layer 2: fused pull means (bf16 h) ----
  pull2_kernel<128, true, 128, true><<<pbA + pbB, tb, 0, stream>>>(
      off_ct, csr_ct, h_cli, mean2_ct, NT, NC,
      off_tc, csr_tc, h_txn, mean2_tc, NC, NT, pbA);

  float* out = (float*)d_out;
  const long long ztxn_base = (long long)NT * 64;
  const long long zcli_base = ztxn_base + (long long)NT * 128;

  // ---- fused: z_txn + decoder (replaces 3 kernels) ----
  gemm_fused_dec_kernel<<<gbm(NT, 4), tb, 0, stream>>>(
      mean2_ct, h_txn, Wt3, b2ct, Wt5, bd1, Wt6, bd2,
      out + ztxn_base, out, NT);

  gemm_kernel<8, 8, 4, AT_BF16, AT_BF16, true, 1><<<gbm(NC, 1), tb, 0, stream>>>(
      mean2_tc, 128, h_cli, 128, Wt4, b2tc, out, zcli_base, 128, NC, 0);
}